// Round 1
// baseline (5847.467 us; speedup 1.0000x reference)
//
#include <hip/hip_runtime.h>
#include <hip/hip_bf16.h>
#include <stdint.h>

#define D_ 128
#define R_ 200
#define B_ 50
#define N_ 100000
#define TE 64

// ---------------- counting / sorting machinery ----------------

__global__ __launch_bounds__(256) void k_count(const int* __restrict__ dst, const int* __restrict__ et,
                                               int E, int* __restrict__ counts) {
  int i = blockIdx.x * 256 + threadIdx.x;
  if (i < E) atomicAdd(&counts[dst[i] * R_ + et[i]], 1);
}

__global__ __launch_bounds__(256) void k_hist(const int* __restrict__ et, int E, int* __restrict__ hist) {
  __shared__ int h[R_];
  for (int i = threadIdx.x; i < R_; i += 256) h[i] = 0;
  __syncthreads();
  int base = blockIdx.x * 4096;
  for (int j = 0; j < 16; j++) {
    int i = base + j * 256 + threadIdx.x;
    if (i < E) atomicAdd(&h[et[i]], 1);
  }
  __syncthreads();
  for (int i = threadIdx.x; i < R_; i += 256) { int v = h[i]; if (v) atomicAdd(&hist[i], v); }
}

__global__ void k_scan(const int* __restrict__ hist, int* __restrict__ padOff, int* __restrict__ cursor) {
  if (threadIdx.x == 0) {
    int off = 0;
    for (int r = 0; r < R_; r++) {
      padOff[r] = off; cursor[r] = off;
      off += ((hist[r] + TE - 1) / TE) * TE;  // pad each relation segment to TE
    }
    padOff[R_] = off;
  }
}

__global__ __launch_bounds__(256) void k_scatter(const int* __restrict__ src, const int* __restrict__ dst,
                                                 const int* __restrict__ et, int E,
                                                 const int* __restrict__ counts, int* __restrict__ cursor,
                                                 int* __restrict__ srcS, int* __restrict__ dstS,
                                                 float* __restrict__ normS) {
  __shared__ int h[R_];
  __shared__ int gb[R_];
  for (int i = threadIdx.x; i < R_; i += 256) h[i] = 0;
  __syncthreads();
  int base = blockIdx.x * 4096;
  int lrank[16];
#pragma unroll
  for (int j = 0; j < 16; j++) {
    int i = base + j * 256 + threadIdx.x;
    lrank[j] = (i < E) ? atomicAdd(&h[et[i]], 1) : 0;
  }
  __syncthreads();
  for (int i = threadIdx.x; i < R_; i += 256) { int v = h[i]; gb[i] = v ? atomicAdd(&cursor[i], v) : 0; }
  __syncthreads();
#pragma unroll
  for (int j = 0; j < 16; j++) {
    int i = base + j * 256 + threadIdx.x;
    if (i < E) {
      int r = et[i], d = dst[i];
      int pos = gb[r] + lrank[j];
      srcS[pos] = src[i];
      dstS[pos] = d;
      int c = counts[d * R_ + r];
      normS[pos] = 1.0f / (float)(c > 1 ? c : 1);
    }
  }
}

// ---------------- W_r = sum_b comp[r,b] * basis[b] ----------------

__global__ __launch_bounds__(256) void k_computeW(const float* __restrict__ comp, const float* __restrict__ basis,
                                                  float* __restrict__ W) {
  __shared__ float c[B_];
  int r = blockIdx.x >> 6;       // D*D/256 = 64 chunks per relation
  int chunk = blockIdx.x & 63;
  if (threadIdx.x < B_) c[threadIdx.x] = comp[r * B_ + threadIdx.x];
  __syncthreads();
  int ij = chunk * 256 + threadIdx.x;
  float acc = 0.f;
#pragma unroll 10
  for (int b = 0; b < B_; b++) acc += c[b] * basis[b * (D_ * D_) + ij];
  W[r * (D_ * D_) + ij] = acc;
}

// ---------------- shared 64x128 fp32 tile GEMM core ----------------
// xs: 64 rows x 128 k (LDS).  Wg: 128x128 row-major (global, L2-hot).
// thread (tx in [0,32): cols 4tx..4tx+3; ty in [0,8): rows ty+8e).

__device__ __forceinline__ void tile_mm(const float (*xs)[D_], const float* __restrict__ Wg,
                                        int tx, int ty, float acc[8][4]) {
#pragma unroll
  for (int e = 0; e < 8; e++) { acc[e][0] = 0.f; acc[e][1] = 0.f; acc[e][2] = 0.f; acc[e][3] = 0.f; }
  for (int k = 0; k < D_; k += 4) {
    float w[4][4];
#pragma unroll
    for (int kk = 0; kk < 4; kk++) {
      float4 t = *(const float4*)(Wg + (k + kk) * D_ + 4 * tx);
      w[kk][0] = t.x; w[kk][1] = t.y; w[kk][2] = t.z; w[kk][3] = t.w;
    }
#pragma unroll
    for (int e = 0; e < 8; e++) {
      float4 xv = *(const float4*)&xs[ty + 8 * e][k];
#pragma unroll
      for (int cc = 0; cc < 4; cc++)
        acc[e][cc] += xv.x * w[0][cc] + xv.y * w[1][cc] + xv.z * w[2][cc] + xv.w * w[3][cc];
    }
  }
}

// ---------------- y = x @ root + bias ----------------

__global__ __launch_bounds__(256) void k_root(const float* __restrict__ x, const float* __restrict__ root,
                                              const float* __restrict__ bias, float* __restrict__ y) {
  __shared__ float xs[TE][D_];
  int row0 = blockIdx.x * TE;
  for (int idx = threadIdx.x; idx < TE * D_; idx += 256) {
    int rr = idx >> 7, cc = idx & 127;
    int gr = row0 + rr;
    xs[rr][cc] = (gr < N_) ? x[gr * D_ + cc] : 0.f;
  }
  __syncthreads();
  int tx = threadIdx.x & 31, ty = threadIdx.x >> 5;
  float acc[8][4];
  tile_mm(xs, root, tx, ty, acc);
  float4 b4 = *(const float4*)(bias + 4 * tx);
#pragma unroll
  for (int e = 0; e < 8; e++) {
    int gr = row0 + ty + 8 * e;
    if (gr < N_) {
      float4 o;
      o.x = acc[e][0] + b4.x; o.y = acc[e][1] + b4.y;
      o.z = acc[e][2] + b4.z; o.w = acc[e][3] + b4.w;
      *(float4*)(y + gr * D_ + 4 * tx) = o;
    }
  }
}

// ---------------- per-edge messages: y[dst] += (x[src]*norm) @ W_rel ----------------

__global__ __launch_bounds__(256) void k_edges(const float* __restrict__ x, const float* __restrict__ W,
                                               const int* __restrict__ srcS, const int* __restrict__ dstS,
                                               const float* __restrict__ normS, const int* __restrict__ padOff,
                                               float* __restrict__ y) {
  __shared__ float xs[TE][D_];
  __shared__ float nrm[TE];
  __shared__ int dsh[TE];
  __shared__ int ssh[TE];
  __shared__ int relsh;
  int base = blockIdx.x * TE;
  if (base >= padOff[R_]) return;
  if (threadIdx.x == 0) {
    int lo = 0, hi = R_ - 1;
    while (lo < hi) { int mid = (lo + hi + 1) >> 1; if (padOff[mid] <= base) lo = mid; else hi = mid - 1; }
    relsh = lo;
  }
  if (threadIdx.x < TE) {
    nrm[threadIdx.x] = normS[base + threadIdx.x];
    dsh[threadIdx.x] = dstS[base + threadIdx.x];
    ssh[threadIdx.x] = srcS[base + threadIdx.x];
  }
  __syncthreads();
  for (int idx = threadIdx.x; idx < TE * D_; idx += 256) {
    int rr = idx >> 7, cc = idx & 127;
    xs[rr][cc] = x[ssh[rr] * D_ + cc] * nrm[rr];  // fold mean-norm into gather
  }
  const float* Wr = W + relsh * (D_ * D_);
  __syncthreads();
  int tx = threadIdx.x & 31, ty = threadIdx.x >> 5;
  float acc[8][4];
  tile_mm(xs, Wr, tx, ty, acc);
#pragma unroll
  for (int e = 0; e < 8; e++) {
    int er = ty + 8 * e;
    if (nrm[er] > 0.f) {  // skip padding slots
      float* yp = y + dsh[er] * D_ + 4 * tx;
      atomicAdd(yp + 0, acc[e][0]);
      atomicAdd(yp + 1, acc[e][1]);
      atomicAdd(yp + 2, acc[e][2]);
      atomicAdd(yp + 3, acc[e][3]);
    }
  }
}

__global__ __launch_bounds__(256) void k_relu(float* __restrict__ y, int n4) {
  int i = blockIdx.x * 256 + threadIdx.x;
  if (i < n4) {
    float4 v = ((float4*)y)[i];
    v.x = v.x > 0.f ? v.x : 0.f;
    v.y = v.y > 0.f ? v.y : 0.f;
    v.z = v.z > 0.f ? v.z : 0.f;
    v.w = v.w > 0.f ? v.w : 0.f;
    ((float4*)y)[i] = v;
  }
}

// ---------------- launch ----------------

extern "C" void kernel_launch(void* const* d_in, const int* in_sizes, int n_in,
                              void* d_out, int out_size, void* d_ws, size_t ws_size,
                              hipStream_t stream) {
  const float* entity = (const float*)d_in[0];
  const float* comp   = (const float*)d_in[1];
  const float* basis  = (const float*)d_in[2];
  const float* root   = (const float*)d_in[3];
  const float* bias   = (const float*)d_in[4];
  const int*   eidx   = (const int*)d_in[5];
  const int*   etype  = (const int*)d_in[6];
  const int E = in_sizes[6];
  const int* src = eidx;
  const int* dst = eidx + E;

  char* ws = (char*)d_ws;
  const size_t Epad = (size_t)E + (size_t)R_ * TE;
  float* W = (float*)ws;
  size_t off = (size_t)R_ * D_ * D_ * 4;                 // 13,107,200 B
  int*   srcS  = (int*)(ws + off);
  int*   dstS  = (int*)(ws + off + Epad * 4);
  float* normS = (float*)(ws + off + Epad * 8);
  int*   smal  = (int*)(ws + off + Epad * 12);
  int*   hist   = smal;
  int*   padOff = smal + 256;
  int*   cursor = smal + 512;
  int*   counts = (int*)(ws + off + Epad * 12 + 4096);   // N*R*4 = 80 MB
  float* x1     = (float*)counts;                        // aliased: counts dead after k_scatter

  size_t zbytes = Epad * 12 + 4096 + (size_t)N_ * R_ * 4;
  hipMemsetAsync(ws + off, 0, zbytes, stream);

  int gE = (E + 255) / 256;
  int gH = (E + 4095) / 4096;
  k_count<<<gE, 256, 0, stream>>>(dst, etype, E, counts);
  k_hist<<<gH, 256, 0, stream>>>(etype, E, hist);
  k_scan<<<1, 64, 0, stream>>>(hist, padOff, cursor);
  k_scatter<<<gH, 256, 0, stream>>>(src, dst, etype, E, counts, cursor, srcS, dstS, normS);

  int gEdge = E / TE + R_;             // upper bound on padded tiles
  int gRoot = (N_ + TE - 1) / TE;
  for (int l = 0; l < 2; l++) {
    const float* xin = l ? x1 : entity;
    float* yout = l ? (float*)d_out : x1;
    k_computeW<<<R_ * 64, 256, 0, stream>>>(comp + l * R_ * B_, basis + (size_t)l * B_ * D_ * D_, W);
    k_root<<<gRoot, 256, 0, stream>>>(xin, root + l * D_ * D_, bias + l * D_, yout);
    k_edges<<<gEdge, 256, 0, stream>>>(xin, W, srcS, dstS, normS, padOff, yout);
    k_relu<<<(N_ * D_ / 4 + 255) / 256, 256, 0, stream>>>(yout, N_ * D_ / 4);
  }
}

// Round 2
// 2749.024 us; speedup vs baseline: 2.1271x; 2.1271x over previous
//
#include <hip/hip_runtime.h>
#include <hip/hip_bf16.h>
#include <stdint.h>

#define D_ 128
#define R_ 200
#define B_ 50
#define N_ 100000
#define TE 64
#define CH 98   // ceil(N_/1024) for the 1-block scan

// ---------------- helpers ----------------

__device__ __forceinline__ ushort f2bf(float f) {   // RTN-even fp32 -> bf16
  uint u = __float_as_uint(f);
  return (ushort)((u + 0x7fffu + ((u >> 16) & 1u)) >> 16);
}
__device__ __forceinline__ float bf2f(ushort u) {
  return __uint_as_float(((uint)u) << 16);
}

// ---------------- counting / sorting machinery ----------------

__global__ __launch_bounds__(256) void k_count(const int* __restrict__ dst, const int* __restrict__ et,
                                               int E, int* __restrict__ counts) {
  int i = blockIdx.x * 256 + threadIdx.x;
  if (i < E) atomicAdd(&counts[dst[i] * R_ + et[i]], 1);
}

__global__ __launch_bounds__(256) void k_hist(const int* __restrict__ et, int E, int* __restrict__ hist) {
  __shared__ int h[R_];
  for (int i = threadIdx.x; i < R_; i += 256) h[i] = 0;
  __syncthreads();
  int base = blockIdx.x * 4096;
  for (int j = 0; j < 16; j++) {
    int i = base + j * 256 + threadIdx.x;
    if (i < E) atomicAdd(&h[et[i]], 1);
  }
  __syncthreads();
  for (int i = threadIdx.x; i < R_; i += 256) { int v = h[i]; if (v) atomicAdd(&hist[i], v); }
}

__global__ void k_scan(const int* __restrict__ hist, int* __restrict__ padOff, int* __restrict__ cursor) {
  if (threadIdx.x == 0) {
    int off = 0;
    for (int r = 0; r < R_; r++) {
      padOff[r] = off; cursor[r] = off;
      off += ((hist[r] + TE - 1) / TE) * TE;  // pad each relation segment to TE
    }
    padOff[R_] = off;
  }
}

__global__ __launch_bounds__(256) void k_scatter(const int* __restrict__ src, const int* __restrict__ dst,
                                                 const int* __restrict__ et, int E,
                                                 const int* __restrict__ counts, int* __restrict__ cursor,
                                                 int* __restrict__ srcS, int* __restrict__ dstS,
                                                 float* __restrict__ normS) {
  __shared__ int h[R_];
  __shared__ int gb[R_];
  for (int i = threadIdx.x; i < R_; i += 256) h[i] = 0;
  __syncthreads();
  int base = blockIdx.x * 4096;
  int lrank[16];
#pragma unroll
  for (int j = 0; j < 16; j++) {
    int i = base + j * 256 + threadIdx.x;
    lrank[j] = (i < E) ? atomicAdd(&h[et[i]], 1) : 0;
  }
  __syncthreads();
  for (int i = threadIdx.x; i < R_; i += 256) { int v = h[i]; gb[i] = v ? atomicAdd(&cursor[i], v) : 0; }
  __syncthreads();
#pragma unroll
  for (int j = 0; j < 16; j++) {
    int i = base + j * 256 + threadIdx.x;
    if (i < E) {
      int r = et[i], d = dst[i];
      int pos = gb[r] + lrank[j];
      srcS[pos] = src[i];
      dstS[pos] = d;
      int c = counts[d * R_ + r];
      normS[pos] = 1.0f / (float)(c > 1 ? c : 1);
    }
  }
}

// ---------------- dst-sort: deg count, 1-block scan, position scatter ----------------

__global__ __launch_bounds__(256) void k_countDst(const int* __restrict__ dst, int E, int* __restrict__ deg) {
  int i = blockIdx.x * 256 + threadIdx.x;
  if (i < E) atomicAdd(&deg[dst[i]], 1);
}

__global__ __launch_bounds__(1024) void k_scanDst(const int* __restrict__ deg,
                                                  int* __restrict__ dstOff, int* __restrict__ cur) {
  __shared__ int s[1024];
  int tid = threadIdx.x;
  int lo = tid * CH;
  int hi = lo + CH; if (hi > N_) hi = N_;
  int sum = 0;
  for (int d = lo; d < hi; d++) sum += deg[d];
  s[tid] = sum;
  __syncthreads();
  for (int off = 1; off < 1024; off <<= 1) {
    int v = (tid >= off) ? s[tid - off] : 0;
    __syncthreads();
    s[tid] += v;
    __syncthreads();
  }
  int run = s[tid] - sum;  // exclusive prefix
  for (int d = lo; d < hi; d++) { dstOff[d] = run; cur[d] = run; run += deg[d]; }
  if (tid == 1023) dstOff[N_] = s[1023];
}

__global__ __launch_bounds__(256) void k_scatterDst(const int* __restrict__ dstS, const float* __restrict__ normS,
                                                    const int* __restrict__ padOff, int* __restrict__ cur,
                                                    int* __restrict__ posbuf) {
  int p = blockIdx.x * 256 + threadIdx.x;
  if (p >= padOff[R_]) return;
  if (normS[p] <= 0.f) return;          // padding slot
  int d = dstS[p];
  int j = atomicAdd(&cur[d], 1);
  posbuf[j] = p;
}

// ---------------- W_r = sum_b comp[r,b] * basis[b] ----------------

__global__ __launch_bounds__(256) void k_computeW(const float* __restrict__ comp, const float* __restrict__ basis,
                                                  float* __restrict__ W) {
  __shared__ float c[B_];
  int r = blockIdx.x >> 6;
  int chunk = blockIdx.x & 63;
  if (threadIdx.x < B_) c[threadIdx.x] = comp[r * B_ + threadIdx.x];
  __syncthreads();
  int ij = chunk * 256 + threadIdx.x;
  float acc = 0.f;
#pragma unroll 10
  for (int b = 0; b < B_; b++) acc += c[b] * basis[b * (D_ * D_) + ij];
  W[r * (D_ * D_) + ij] = acc;
}

// ---------------- shared 64x128 fp32 tile GEMM core ----------------

__device__ __forceinline__ void tile_mm(const float (*xs)[D_], const float* __restrict__ Wg,
                                        int tx, int ty, float acc[8][4]) {
#pragma unroll
  for (int e = 0; e < 8; e++) { acc[e][0] = 0.f; acc[e][1] = 0.f; acc[e][2] = 0.f; acc[e][3] = 0.f; }
  for (int k = 0; k < D_; k += 4) {
    float w[4][4];
#pragma unroll
    for (int kk = 0; kk < 4; kk++) {
      float4 t = *(const float4*)(Wg + (k + kk) * D_ + 4 * tx);
      w[kk][0] = t.x; w[kk][1] = t.y; w[kk][2] = t.z; w[kk][3] = t.w;
    }
#pragma unroll
    for (int e = 0; e < 8; e++) {
      float4 xv = *(const float4*)&xs[ty + 8 * e][k];
#pragma unroll
      for (int cc = 0; cc < 4; cc++)
        acc[e][cc] += xv.x * w[0][cc] + xv.y * w[1][cc] + xv.z * w[2][cc] + xv.w * w[3][cc];
    }
  }
}

// ---------------- y = x @ root + bias ----------------

__global__ __launch_bounds__(256) void k_root(const float* __restrict__ x, const float* __restrict__ root,
                                              const float* __restrict__ bias, float* __restrict__ y) {
  __shared__ float xs[TE][D_];
  int row0 = blockIdx.x * TE;
  for (int idx = threadIdx.x; idx < TE * D_; idx += 256) {
    int rr = idx >> 7, cc = idx & 127;
    int gr = row0 + rr;
    xs[rr][cc] = (gr < N_) ? x[gr * D_ + cc] : 0.f;
  }
  __syncthreads();
  int tx = threadIdx.x & 31, ty = threadIdx.x >> 5;
  float acc[8][4];
  tile_mm(xs, root, tx, ty, acc);
  float4 b4 = *(const float4*)(bias + 4 * tx);
#pragma unroll
  for (int e = 0; e < 8; e++) {
    int gr = row0 + ty + 8 * e;
    if (gr < N_) {
      float4 o;
      o.x = acc[e][0] + b4.x; o.y = acc[e][1] + b4.y;
      o.z = acc[e][2] + b4.z; o.w = acc[e][3] + b4.w;
      *(float4*)(y + (size_t)gr * D_ + 4 * tx) = o;
    }
  }
}

// ---------------- phase A: msg[pos] = (x[src]*norm) @ W_rel  (bf16 out) ----------------

__global__ __launch_bounds__(256) void k_edges_msg(const float* __restrict__ x, const float* __restrict__ W,
                                                   const int* __restrict__ srcS, const float* __restrict__ normS,
                                                   const int* __restrict__ padOff,
                                                   ushort* __restrict__ msg, int tile0) {
  __shared__ float xs[TE][D_];
  __shared__ float nrm[TE];
  __shared__ int ssh[TE];
  __shared__ int relsh;
  int tile = tile0 + blockIdx.x;
  int base = tile * TE;
  if (base >= padOff[R_]) return;
  if (threadIdx.x == 0) {
    int lo = 0, hi = R_ - 1;
    while (lo < hi) { int mid = (lo + hi + 1) >> 1; if (padOff[mid] <= base) lo = mid; else hi = mid - 1; }
    relsh = lo;
  }
  if (threadIdx.x < TE) {
    nrm[threadIdx.x] = normS[base + threadIdx.x];
    ssh[threadIdx.x] = srcS[base + threadIdx.x];
  }
  __syncthreads();
  for (int idx = threadIdx.x; idx < TE * D_; idx += 256) {
    int rr = idx >> 7, cc = idx & 127;
    xs[rr][cc] = x[(size_t)ssh[rr] * D_ + cc] * nrm[rr];
  }
  const float* Wr = W + relsh * (D_ * D_);
  __syncthreads();
  int tx = threadIdx.x & 31, ty = threadIdx.x >> 5;
  float acc[8][4];
  tile_mm(xs, Wr, tx, ty, acc);
  size_t lbase = (size_t)(base - tile0 * TE);
#pragma unroll
  for (int e = 0; e < 8; e++) {
    int er = ty + 8 * e;
    if (nrm[er] > 0.f) {
      ushort4 o;
      o.x = f2bf(acc[e][0]); o.y = f2bf(acc[e][1]);
      o.z = f2bf(acc[e][2]); o.w = f2bf(acc[e][3]);
      *(ushort4*)(msg + ((lbase + er) << 7) + (tx << 2)) = o;
    }
  }
}

// ---------------- phase B: y[d] += sum of msgs; relu on final chunk ----------------

__global__ __launch_bounds__(256) void k_agg(const ushort* __restrict__ msg, const int* __restrict__ posbuf,
                                             const int* __restrict__ dstOff, float* __restrict__ y,
                                             int lo, int hi, int final_) {
  int d = blockIdx.x * 16 + (threadIdx.x >> 4);
  if (d >= N_) return;
  int tx = threadIdx.x & 15;                 // 16 lanes x 8 cols = 128
  int s0 = dstOff[d], s1 = dstOff[d + 1];
  float acc[8];
#pragma unroll
  for (int i = 0; i < 8; i++) acc[i] = 0.f;
  for (int j = s0; j < s1; j++) {
    int p = posbuf[j];
    if (p < lo || p >= hi) continue;
    const ushort4* mrow = (const ushort4*)(msg + (((size_t)(p - lo)) << 7) + (tx << 3));
    ushort4 a = mrow[0], b = mrow[1];
    acc[0] += bf2f(a.x); acc[1] += bf2f(a.y); acc[2] += bf2f(a.z); acc[3] += bf2f(a.w);
    acc[4] += bf2f(b.x); acc[5] += bf2f(b.y); acc[6] += bf2f(b.z); acc[7] += bf2f(b.w);
  }
  float* yp = y + ((size_t)d << 7) + (tx << 3);
  float4 y0 = *(float4*)yp, y1 = *(float4*)(yp + 4);
  y0.x += acc[0]; y0.y += acc[1]; y0.z += acc[2]; y0.w += acc[3];
  y1.x += acc[4]; y1.y += acc[5]; y1.z += acc[6]; y1.w += acc[7];
  if (final_) {
    y0.x = fmaxf(y0.x, 0.f); y0.y = fmaxf(y0.y, 0.f); y0.z = fmaxf(y0.z, 0.f); y0.w = fmaxf(y0.w, 0.f);
    y1.x = fmaxf(y1.x, 0.f); y1.y = fmaxf(y1.y, 0.f); y1.z = fmaxf(y1.z, 0.f); y1.w = fmaxf(y1.w, 0.f);
  }
  *(float4*)yp = y0; *(float4*)(yp + 4) = y1;
}

// ---------------- launch ----------------

extern "C" void kernel_launch(void* const* d_in, const int* in_sizes, int n_in,
                              void* d_out, int out_size, void* d_ws, size_t ws_size,
                              hipStream_t stream) {
  const float* entity = (const float*)d_in[0];
  const float* comp   = (const float*)d_in[1];
  const float* basis  = (const float*)d_in[2];
  const float* root   = (const float*)d_in[3];
  const float* bias   = (const float*)d_in[4];
  const int*   eidx   = (const int*)d_in[5];
  const int*   etype  = (const int*)d_in[6];
  const int E = in_sizes[6];
  const int* src = eidx;
  const int* dst = eidx + E;

  char* ws = (char*)d_ws;
  const size_t Epad = (size_t)E + (size_t)R_ * TE;

  // layout
  size_t o_W      = 0;
  size_t o_srcS   = o_W + (size_t)R_ * D_ * D_ * 4;
  size_t o_dstS   = o_srcS + Epad * 4;
  size_t o_normS  = o_dstS + Epad * 4;
  size_t o_posbuf = o_normS + Epad * 4;
  size_t o_degDst = o_posbuf + (size_t)E * 4;
  size_t o_dstOff = o_degDst + (size_t)N_ * 4;
  size_t o_cursD  = o_dstOff + (size_t)(N_ + 8) * 4;
  size_t o_small  = o_cursD + (size_t)N_ * 4;
  size_t o_counts = o_small + 4096;
  size_t o_x1     = o_counts;                                     // x1 aliases counts (dead after sort)
  size_t o_msg    = (o_counts + (size_t)N_ * 128 * 4 + 255) & ~(size_t)255;  // msg after x1 (51.2MB)
  size_t countsEnd = o_counts + (size_t)N_ * R_ * 4;              // 80MB (overlaps msg; counts dead first)

  float* W      = (float*)(ws + o_W);
  int*   srcS   = (int*)(ws + o_srcS);
  int*   dstS   = (int*)(ws + o_dstS);
  float* normS  = (float*)(ws + o_normS);
  int*   posbuf = (int*)(ws + o_posbuf);
  int*   degDst = (int*)(ws + o_degDst);
  int*   dstOff = (int*)(ws + o_dstOff);
  int*   cursD  = (int*)(ws + o_cursD);
  int*   hist   = (int*)(ws + o_small);
  int*   padOff = hist + 256;
  int*   cursor = hist + 512;
  int*   counts = (int*)(ws + o_counts);
  float* x1     = (float*)(ws + o_x1);
  ushort* msg   = (ushort*)(ws + o_msg);

  hipMemsetAsync(ws + o_srcS, 0, countsEnd - o_srcS, stream);

  int gE = (E + 255) / 256;
  int gH = (E + 4095) / 4096;
  k_count<<<gE, 256, 0, stream>>>(dst, etype, E, counts);
  k_hist<<<gH, 256, 0, stream>>>(etype, E, hist);
  k_scan<<<1, 64, 0, stream>>>(hist, padOff, cursor);
  k_scatter<<<gH, 256, 0, stream>>>(src, dst, etype, E, counts, cursor, srcS, dstS, normS);
  k_countDst<<<gE, 256, 0, stream>>>(dst, E, degDst);
  k_scanDst<<<1, 1024, 0, stream>>>(degDst, dstOff, cursD);
  int uTiles = (E + TE - 1) / TE + R_;
  int uBlocks = (uTiles * TE + 255) / 256;
  k_scatterDst<<<uBlocks, 256, 0, stream>>>(dstS, normS, padOff, cursD, posbuf);

  // chunking (adapts to ws_size; 1 chunk when ws >= ~505MB)
  size_t cap = (ws_size > o_msg + 16384) ? (ws_size - o_msg) : (size_t)16384;
  size_t tileBytes = (size_t)TE * D_ * 2;
  int maxTilesPerChunk = (int)(cap / tileBytes);
  if (maxTilesPerChunk < 1) maxTilesPerChunk = 1;
  int nchunks = (uTiles + maxTilesPerChunk - 1) / maxTilesPerChunk;
  int chunkTiles = (uTiles + nchunks - 1) / nchunks;
  nchunks = (uTiles + chunkTiles - 1) / chunkTiles;

  int gRoot = (N_ + TE - 1) / TE;
  int gAgg = (N_ + 15) / 16;
  for (int l = 0; l < 2; l++) {
    const float* xin = l ? x1 : entity;
    float* yout = l ? (float*)d_out : x1;
    k_computeW<<<R_ * 64, 256, 0, stream>>>(comp + l * R_ * B_, basis + (size_t)l * B_ * D_ * D_, W);
    k_root<<<gRoot, 256, 0, stream>>>(xin, root + l * D_ * D_, bias + l * D_, yout);
    for (int c = 0; c < nchunks; c++) {
      int t0 = c * chunkTiles;
      int t1 = t0 + chunkTiles; if (t1 > uTiles) t1 = uTiles;
      k_edges_msg<<<t1 - t0, 256, 0, stream>>>(xin, W, srcS, normS, padOff, msg, t0);
      k_agg<<<gAgg, 256, 0, stream>>>(msg, posbuf, dstOff, yout, t0 * TE, t1 * TE, c == nchunks - 1);
    }
  }
}

// Round 3
// 1547.460 us; speedup vs baseline: 3.7788x; 1.7765x over previous
//
#include <hip/hip_runtime.h>
#include <hip/hip_bf16.h>
#include <stdint.h>

#define D_ 128
#define R_ 200
#define B_ 50
#define N_ 100000
#define TE 64
#define G_ 8
#define MAXC 8
#define CH 98   // ceil(N_/1024) for the 1-block scan

typedef __attribute__((ext_vector_type(8))) short s8b;
typedef __attribute__((ext_vector_type(4))) float f32x4;

// ---------------- helpers ----------------

__device__ __forceinline__ ushort f2bf(float f) {   // RTN-even fp32 -> bf16
  uint u = __float_as_uint(f);
  return (ushort)((u + 0x7fffu + ((u >> 16) & 1u)) >> 16);
}
__device__ __forceinline__ float bf2f(ushort u) {
  return __uint_as_float(((uint)u) << 16);
}

// ---------------- counting / sorting machinery ----------------

__global__ __launch_bounds__(256) void k_count(const int* __restrict__ dst, const int* __restrict__ et,
                                               int E, int* __restrict__ counts) {
  int i = blockIdx.x * 256 + threadIdx.x;
  if (i < E) atomicAdd(&counts[dst[i] * R_ + et[i]], 1);
}

__global__ __launch_bounds__(256) void k_hist(const int* __restrict__ et, int E, int* __restrict__ hist) {
  __shared__ int h[R_];
  for (int i = threadIdx.x; i < R_; i += 256) h[i] = 0;
  __syncthreads();
  int base = blockIdx.x * 4096;
  for (int j = 0; j < 16; j++) {
    int i = base + j * 256 + threadIdx.x;
    if (i < E) atomicAdd(&h[et[i]], 1);
  }
  __syncthreads();
  for (int i = threadIdx.x; i < R_; i += 256) { int v = h[i]; if (v) atomicAdd(&hist[i], v); }
}

__global__ void k_scan(const int* __restrict__ hist, int* __restrict__ padOff, int* __restrict__ cursor) {
  if (threadIdx.x == 0) {
    int off = 0;
    for (int r = 0; r < R_; r++) {
      padOff[r] = off; cursor[r] = off;
      off += ((hist[r] + TE - 1) / TE) * TE;
    }
    padOff[R_] = off;
  }
}

__global__ __launch_bounds__(256) void k_scatter(const int* __restrict__ src, const int* __restrict__ dst,
                                                 const int* __restrict__ et, int E,
                                                 const int* __restrict__ counts, int* __restrict__ cursor,
                                                 int* __restrict__ srcS, int* __restrict__ dstS,
                                                 float* __restrict__ normS) {
  __shared__ int h[R_];
  __shared__ int gb[R_];
  for (int i = threadIdx.x; i < R_; i += 256) h[i] = 0;
  __syncthreads();
  int base = blockIdx.x * 4096;
  int lrank[16];
#pragma unroll
  for (int j = 0; j < 16; j++) {
    int i = base + j * 256 + threadIdx.x;
    lrank[j] = (i < E) ? atomicAdd(&h[et[i]], 1) : 0;
  }
  __syncthreads();
  for (int i = threadIdx.x; i < R_; i += 256) { int v = h[i]; gb[i] = v ? atomicAdd(&cursor[i], v) : 0; }
  __syncthreads();
#pragma unroll
  for (int j = 0; j < 16; j++) {
    int i = base + j * 256 + threadIdx.x;
    if (i < E) {
      int r = et[i], d = dst[i];
      int pos = gb[r] + lrank[j];
      srcS[pos] = src[i];
      dstS[pos] = d;
      int c = counts[d * R_ + r];
      normS[pos] = 1.0f / (float)(c > 1 ? c : 1);
    }
  }
}

__global__ __launch_bounds__(256) void k_tileRel(const int* __restrict__ padOff, int* __restrict__ tileRel, int uT) {
  int t = blockIdx.x * 256 + threadIdx.x;
  if (t >= uT) return;
  int base = t * TE;
  if (base >= padOff[R_]) { tileRel[t] = 0; return; }
  int lo = 0, hi = R_ - 1;
  while (lo < hi) { int mid = (lo + hi + 1) >> 1; if (padOff[mid] <= base) lo = mid; else hi = mid - 1; }
  tileRel[t] = lo;
}

// ---------------- dst-sort ----------------

__global__ __launch_bounds__(256) void k_countDst(const int* __restrict__ dst, int E, int* __restrict__ deg) {
  int i = blockIdx.x * 256 + threadIdx.x;
  if (i < E) atomicAdd(&deg[dst[i]], 1);
}

__global__ __launch_bounds__(1024) void k_scanDst(const int* __restrict__ deg,
                                                  int* __restrict__ dstOff, int* __restrict__ cur) {
  __shared__ int s[1024];
  int tid = threadIdx.x;
  int lo = tid * CH;
  int hi = lo + CH; if (hi > N_) hi = N_;
  int sum = 0;
  for (int d = lo; d < hi; d++) sum += deg[d];
  s[tid] = sum;
  __syncthreads();
  for (int off = 1; off < 1024; off <<= 1) {
    int v = (tid >= off) ? s[tid - off] : 0;
    __syncthreads();
    s[tid] += v;
    __syncthreads();
  }
  int run = s[tid] - sum;
  for (int d = lo; d < hi; d++) { dstOff[d] = run; cur[d] = run; run += deg[d]; }
  if (tid == 1023) dstOff[N_] = s[1023];
}

__global__ __launch_bounds__(256) void k_scatterDst(const int* __restrict__ dstS, const float* __restrict__ normS,
                                                    const int* __restrict__ padOff, int* __restrict__ cur,
                                                    int* __restrict__ posbuf, int plo, int phi) {
  int p = plo + blockIdx.x * 256 + threadIdx.x;
  if (p >= phi || p >= padOff[R_]) return;
  if (normS[p] <= 0.f) return;
  int d = dstS[p];
  int j = atomicAdd(&cur[d], 1);
  posbuf[j] = p;
}

__global__ __launch_bounds__(256) void k_copyBound(const int* __restrict__ cur, int* __restrict__ bnd) {
  int d = blockIdx.x * 256 + threadIdx.x;
  if (d < N_) bnd[d] = cur[d];
}

// ---------------- W_r = sum_b comp[r,b]*basis[b]; pack to B-fragment order ----------------

__global__ __launch_bounds__(256) void k_computeW(const float* __restrict__ comp, const float* __restrict__ basis,
                                                  float* __restrict__ W) {
  __shared__ float c[B_];
  int r = blockIdx.x >> 6;
  int chunk = blockIdx.x & 63;
  if (threadIdx.x < B_) c[threadIdx.x] = comp[r * B_ + threadIdx.x];
  __syncthreads();
  int ij = chunk * 256 + threadIdx.x;
  float acc = 0.f;
#pragma unroll 10
  for (int b = 0; b < B_; b++) acc += c[b] * basis[b * (D_ * D_) + ij];
  W[r * (D_ * D_) + ij] = acc;
}

// pack: Wpack[r][ks][cg][lane][j] = bf16(W[r][ks*32+(lane>>4)*8+j][cg*16+(lane&15)])
__global__ __launch_bounds__(256) void k_packW(const float* __restrict__ W, ushort* __restrict__ Wpack) {
  int r = blockIdx.x;
  const float* Wr = W + (size_t)r * (D_ * D_);
  ushort* out = Wpack + (size_t)r * (D_ * D_);
  for (int i = threadIdx.x; i < D_ * D_; i += 256) {
    int j = i & 7, l = (i >> 3) & 63, cg = (i >> 9) & 7, ks = i >> 12;
    int k = ks * 32 + (l >> 4) * 8 + j;
    int n = cg * 16 + (l & 15);
    out[i] = f2bf(Wr[k * D_ + n]);
  }
}

__global__ __launch_bounds__(256) void k_cast(const float* __restrict__ x, ushort* __restrict__ xb, int n8) {
  int i = blockIdx.x * 256 + threadIdx.x;
  if (i >= n8) return;
  const float4* xp = (const float4*)(x + (size_t)i * 8);
  float4 a = xp[0], b = xp[1];
  uint4 pk;
  pk.x = (uint)f2bf(a.x) | ((uint)f2bf(a.y) << 16);
  pk.y = (uint)f2bf(a.z) | ((uint)f2bf(a.w) << 16);
  pk.z = (uint)f2bf(b.x) | ((uint)f2bf(b.y) << 16);
  pk.w = (uint)f2bf(b.z) | ((uint)f2bf(b.w) << 16);
  *(uint4*)(xb + (size_t)i * 8) = pk;
}

// ---------------- fp32 tile core (root GEMM only) ----------------

__device__ __forceinline__ void tile_mm(const float (*xs)[D_], const float* __restrict__ Wg,
                                        int tx, int ty, float acc[8][4]) {
#pragma unroll
  for (int e = 0; e < 8; e++) { acc[e][0] = 0.f; acc[e][1] = 0.f; acc[e][2] = 0.f; acc[e][3] = 0.f; }
  for (int k = 0; k < D_; k += 4) {
    float w[4][4];
#pragma unroll
    for (int kk = 0; kk < 4; kk++) {
      float4 t = *(const float4*)(Wg + (k + kk) * D_ + 4 * tx);
      w[kk][0] = t.x; w[kk][1] = t.y; w[kk][2] = t.z; w[kk][3] = t.w;
    }
#pragma unroll
    for (int e = 0; e < 8; e++) {
      float4 xv = *(const float4*)&xs[ty + 8 * e][k];
#pragma unroll
      for (int cc = 0; cc < 4; cc++)
        acc[e][cc] += xv.x * w[0][cc] + xv.y * w[1][cc] + xv.z * w[2][cc] + xv.w * w[3][cc];
    }
  }
}

__global__ __launch_bounds__(256) void k_root(const float* __restrict__ x, const float* __restrict__ root,
                                              const float* __restrict__ bias, float* __restrict__ y) {
  __shared__ float xs[TE][D_];
  int row0 = blockIdx.x * TE;
  for (int idx = threadIdx.x; idx < TE * D_; idx += 256) {
    int rr = idx >> 7, cc = idx & 127;
    int gr = row0 + rr;
    xs[rr][cc] = (gr < N_) ? x[(size_t)gr * D_ + cc] : 0.f;
  }
  __syncthreads();
  int tx = threadIdx.x & 31, ty = threadIdx.x >> 5;
  float acc[8][4];
  tile_mm(xs, root, tx, ty, acc);
  float4 b4 = *(const float4*)(bias + 4 * tx);
#pragma unroll
  for (int e = 0; e < 8; e++) {
    int gr = row0 + ty + 8 * e;
    if (gr < N_) {
      float4 o;
      o.x = acc[e][0] + b4.x; o.y = acc[e][1] + b4.y;
      o.z = acc[e][2] + b4.z; o.w = acc[e][3] + b4.w;
      *(float4*)(y + (size_t)gr * D_ + 4 * tx) = o;
    }
  }
}

// ---------------- phase A: MFMA edge messages ----------------
// 4 waves/block, wave w owns rows 16w..16w+15 of each 64-row tile, all 128 cols.
// W fragments held in 128 VGPRs across G_ tiles of the same relation.

__global__ __launch_bounds__(256) void k_edges_mfma(
    const ushort* __restrict__ xb, const ushort* __restrict__ Wpack,
    const int* __restrict__ srcS, const float* __restrict__ normS,
    const int* __restrict__ tileRel, const int* __restrict__ padOff,
    ushort* __restrict__ msg, int tile0, int tile1) {
  int padTot = padOff[R_];
  int tstart = tile0 + blockIdx.x * G_;
  if (tstart >= tile1 || tstart * TE >= padTot) return;
  int tend = tstart + G_; if (tend > tile1) tend = tile1;
  int w = threadIdx.x >> 6, l = threadIdx.x & 63;
  int q = l >> 4, tx = l & 15;
  int curRel = -1;
  s8b b[4][8];
  for (int tile = tstart; tile < tend; ++tile) {
    int base = tile * TE;
    if (base >= padTot) break;
    int rel = tileRel[tile];
    if (rel != curRel) {
      curRel = rel;
      const s8b* wp = (const s8b*)(Wpack + (size_t)rel * (D_ * D_));
#pragma unroll
      for (int ks = 0; ks < 4; ++ks)
#pragma unroll
        for (int cg = 0; cg < 8; ++cg)
          b[ks][cg] = wp[(ks * 8 + cg) * 64 + l];
    }
    int rowA = base + 16 * w + tx;
    int srcRow = srcS[rowA];
    const s8b* xr = (const s8b*)(xb + (size_t)srcRow * D_);
    s8b a0 = xr[q], a1 = xr[4 + q], a2 = xr[8 + q], a3 = xr[12 + q];
    f32x4 acc[8];
#pragma unroll
    for (int cg = 0; cg < 8; ++cg) acc[cg] = (f32x4){0.f, 0.f, 0.f, 0.f};
#pragma unroll
    for (int cg = 0; cg < 8; ++cg) {
      acc[cg] = __builtin_amdgcn_mfma_f32_16x16x32_bf16(a0, b[0][cg], acc[cg], 0, 0, 0);
      acc[cg] = __builtin_amdgcn_mfma_f32_16x16x32_bf16(a1, b[1][cg], acc[cg], 0, 0, 0);
      acc[cg] = __builtin_amdgcn_mfma_f32_16x16x32_bf16(a2, b[2][cg], acc[cg], 0, 0, 0);
      acc[cg] = __builtin_amdgcn_mfma_f32_16x16x32_bf16(a3, b[3][cg], acc[cg], 0, 0, 0);
    }
    float nv[4];
#pragma unroll
    for (int r = 0; r < 4; ++r) nv[r] = normS[base + 16 * w + 4 * q + r];
    size_t rowBase = (size_t)(tile - tile0) * TE + 16 * w;
#pragma unroll
    for (int cg = 0; cg < 8; ++cg) {
      int col = cg * 16 + tx;
#pragma unroll
      for (int r = 0; r < 4; ++r) {
        float v = acc[cg][r] * nv[r];
        msg[(rowBase + 4 * q + r) * D_ + col] = f2bf(v);
      }
    }
  }
}

// ---------------- phase B: wave-per-dst aggregation ----------------

__global__ __launch_bounds__(256) void k_agg2(const ushort* __restrict__ msg, const int* __restrict__ posbuf,
                                              const int* __restrict__ jlo, const int* __restrict__ jhi,
                                              float* __restrict__ y, int plo, int final_) {
  int d = blockIdx.x * 4 + (threadIdx.x >> 6);
  if (d >= N_) return;
  int l = threadIdx.x & 63, sub = l >> 4, tx = l & 15;
  int s0 = jlo[d], s1 = jhi[d];
  float acc[8];
#pragma unroll
  for (int i = 0; i < 8; ++i) acc[i] = 0.f;
  for (int j = s0 + sub; j < s1; j += 4) {
    int p = posbuf[j];
    uint4 mv = *(const uint4*)(msg + (((size_t)(p - plo)) << 7) + (tx << 3));
    acc[0] += bf2f((ushort)mv.x); acc[1] += bf2f((ushort)(mv.x >> 16));
    acc[2] += bf2f((ushort)mv.y); acc[3] += bf2f((ushort)(mv.y >> 16));
    acc[4] += bf2f((ushort)mv.z); acc[5] += bf2f((ushort)(mv.z >> 16));
    acc[6] += bf2f((ushort)mv.w); acc[7] += bf2f((ushort)(mv.w >> 16));
  }
#pragma unroll
  for (int i = 0; i < 8; ++i) {
    acc[i] += __shfl_xor(acc[i], 16);
    acc[i] += __shfl_xor(acc[i], 32);
  }
  if (sub == 0) {
    float* yp = y + (((size_t)d) << 7) + (tx << 3);
    float4 y0 = *(float4*)yp, y1 = *(float4*)(yp + 4);
    y0.x += acc[0]; y0.y += acc[1]; y0.z += acc[2]; y0.w += acc[3];
    y1.x += acc[4]; y1.y += acc[5]; y1.z += acc[6]; y1.w += acc[7];
    if (final_) {
      y0.x = fmaxf(y0.x, 0.f); y0.y = fmaxf(y0.y, 0.f); y0.z = fmaxf(y0.z, 0.f); y0.w = fmaxf(y0.w, 0.f);
      y1.x = fmaxf(y1.x, 0.f); y1.y = fmaxf(y1.y, 0.f); y1.z = fmaxf(y1.z, 0.f); y1.w = fmaxf(y1.w, 0.f);
    }
    *(float4*)yp = y0; *(float4*)(yp + 4) = y1;
  }
}

// ---------------- launch ----------------

extern "C" void kernel_launch(void* const* d_in, const int* in_sizes, int n_in,
                              void* d_out, int out_size, void* d_ws, size_t ws_size,
                              hipStream_t stream) {
  const float* entity = (const float*)d_in[0];
  const float* comp   = (const float*)d_in[1];
  const float* basis  = (const float*)d_in[2];
  const float* root   = (const float*)d_in[3];
  const float* bias   = (const float*)d_in[4];
  const int*   eidx   = (const int*)d_in[5];
  const int*   etype  = (const int*)d_in[6];
  const int E = in_sizes[6];
  const int* src = eidx;
  const int* dst = eidx + E;

  char* ws = (char*)d_ws;
  const size_t Epad = (size_t)E + (size_t)R_ * TE;
  const int uTiles = (E + TE - 1) / TE + R_;
  auto al = [](size_t x) { return (x + 255) & ~(size_t)255; };

  size_t o_Wpack  = 0;
  size_t o_srcS   = al(o_Wpack + (size_t)R_ * D_ * D_ * 2);
  size_t o_normS  = al(o_srcS + Epad * 4);
  size_t o_posbuf = al(o_normS + Epad * 4);
  size_t o_degDst = al(o_posbuf + (size_t)E * 4);
  size_t o_dstOff = al(o_degDst + (size_t)N_ * 4);
  size_t o_cursD  = al(o_dstOff + (size_t)(N_ + 8) * 4);
  size_t o_bounds = al(o_cursD + (size_t)N_ * 4);
  size_t o_tileRel= al(o_bounds + (size_t)MAXC * N_ * 4);
  size_t o_small  = al(o_tileRel + (size_t)uTiles * 4);
  size_t o_x1     = al(o_small + 4096);
  size_t o_xb     = al(o_x1 + (size_t)N_ * D_ * 4);
  size_t o_msg    = al(o_xb + (size_t)N_ * D_ * 2);

  // aliases inside the msg region (all dead before first msg write):
  size_t o_counts = o_msg;                                   // N*R*4 = 80MB, dead after k_scatter
  size_t o_dstS   = al(o_counts + (size_t)N_ * R_ * 4);      // dead after k_scatterDst passes
  size_t o_Wf     = o_msg;                                   // per-layer, dead after k_packW

  ushort* Wpack  = (ushort*)(ws + o_Wpack);
  int*    srcS   = (int*)(ws + o_srcS);
  float*  normS  = (float*)(ws + o_normS);
  int*    posbuf = (int*)(ws + o_posbuf);
  int*    degDst = (int*)(ws + o_degDst);
  int*    dstOff = (int*)(ws + o_dstOff);
  int*    cursD  = (int*)(ws + o_cursD);
  int*    bounds = (int*)(ws + o_bounds);
  int*    tileRel= (int*)(ws + o_tileRel);
  int*    hist   = (int*)(ws + o_small);
  int*    padOff = hist + 256;
  int*    cursor = hist + 512;
  float*  x1     = (float*)(ws + o_x1);
  ushort* xb     = (ushort*)(ws + o_xb);
  int*    counts = (int*)(ws + o_counts);
  int*    dstS   = (int*)(ws + o_dstS);
  float*  Wf     = (float*)(ws + o_Wf);
  ushort* msg    = (ushort*)(ws + o_msg);

  // zero: srcS+normS (padding), degDst, small, counts
  hipMemsetAsync(ws + o_srcS, 0, o_posbuf - o_srcS, stream);
  hipMemsetAsync(ws + o_degDst, 0, (size_t)N_ * 4, stream);
  hipMemsetAsync(ws + o_small, 0, 4096, stream);
  hipMemsetAsync(ws + o_counts, 0, (size_t)N_ * R_ * 4, stream);

  int gE = (E + 255) / 256;
  int gH = (E + 4095) / 4096;
  k_count<<<gE, 256, 0, stream>>>(dst, etype, E, counts);
  k_hist<<<gH, 256, 0, stream>>>(etype, E, hist);
  k_scan<<<1, 64, 0, stream>>>(hist, padOff, cursor);
  k_scatter<<<gH, 256, 0, stream>>>(src, dst, etype, E, counts, cursor, srcS, dstS, normS);
  k_tileRel<<<(uTiles + 255) / 256, 256, 0, stream>>>(padOff, tileRel, uTiles);
  k_countDst<<<gE, 256, 0, stream>>>(dst, E, degDst);
  k_scanDst<<<1, 1024, 0, stream>>>(degDst, dstOff, cursD);

  // chunking from ws capacity
  size_t cap = (ws_size > o_msg + 16384) ? (ws_size - o_msg) : (size_t)16384;
  size_t tileBytes = (size_t)TE * D_ * 2;
  long long maxT = (long long)(cap / tileBytes);
  if (maxT < 1) maxT = 1;
  int nch = (int)((uTiles + maxT - 1) / maxT);
  if (nch < 1) nch = 1;
  if (nch > MAXC) nch = MAXC;
  int chunkTiles = (uTiles + nch - 1) / nch;
  nch = (uTiles + chunkTiles - 1) / chunkTiles;

  // chunk-major posbuf: scatter per chunk, snapshot cursors
  for (int c = 0; c < nch; c++) {
    int plo = c * chunkTiles * TE;
    int phi = (c + 1) * chunkTiles * TE; if (phi > uTiles * TE) phi = uTiles * TE;
    int gS = (phi - plo + 255) / 256;
    if (gS > 0)
      k_scatterDst<<<gS, 256, 0, stream>>>(dstS, normS, padOff, cursD, posbuf, plo, phi);
    k_copyBound<<<(N_ + 255) / 256, 256, 0, stream>>>(cursD, bounds + (size_t)c * N_);
  }

  int gRoot = (N_ + TE - 1) / TE;
  int gAgg = (N_ + 3) / 4;
  for (int l = 0; l < 2; l++) {
    const float* xin = l ? x1 : entity;
    float* yout = l ? (float*)d_out : x1;
    k_computeW<<<R_ * 64, 256, 0, stream>>>(comp + l * R_ * B_, basis + (size_t)l * B_ * D_ * D_, Wf);
    k_packW<<<R_, 256, 0, stream>>>(Wf, Wpack);
    k_cast<<<(N_ * D_ / 8 + 255) / 256, 256, 0, stream>>>(xin, xb, N_ * D_ / 8);
    k_root<<<gRoot, 256, 0, stream>>>(xin, root + l * D_ * D_, bias + l * D_, yout);
    for (int c = 0; c < nch; c++) {
      int t0 = c * chunkTiles;
      int t1 = t0 + chunkTiles; if (t1 > uTiles) t1 = uTiles;
      int gB = (t1 - t0 + G_ - 1) / G_;
      k_edges_mfma<<<gB, 256, 0, stream>>>(xb, Wpack, srcS, normS, tileRel, padOff, msg, t0, t1);
      const int* jlo = (c == 0) ? dstOff : bounds + (size_t)(c - 1) * N_;
      const int* jhi = bounds + (size_t)c * N_;
      k_agg2<<<gAgg, 256, 0, stream>>>(msg, posbuf, jlo, jhi, yout, t0 * TE, c == nch - 1);
    }
  }
}

// Round 4
// 1313.176 us; speedup vs baseline: 4.4529x; 1.1784x over previous
//
#include <hip/hip_runtime.h>
#include <hip/hip_bf16.h>
#include <stdint.h>

#define D_ 128
#define R_ 200
#define B_ 50
#define N_ 100000
#define TE 64
#define G_ 8
#define MAXC 8

typedef __attribute__((ext_vector_type(8))) short s8b;
typedef __attribute__((ext_vector_type(4))) float f32x4;

// ---------------- helpers ----------------

__device__ __forceinline__ ushort f2bf(float f) {   // RTN-even fp32 -> bf16
  uint u = __float_as_uint(f);
  return (ushort)((u + 0x7fffu + ((u >> 16) & 1u)) >> 16);
}
__device__ __forceinline__ float bf2f(ushort u) {
  return __uint_as_float(((uint)u) << 16);
}

// ---------------- counting / sorting machinery ----------------

__global__ __launch_bounds__(256) void k_count(const int* __restrict__ dst, const int* __restrict__ et,
                                               int E, int* __restrict__ counts) {
  int i = blockIdx.x * 256 + threadIdx.x;
  if (i < E) atomicAdd(&counts[dst[i] * R_ + et[i]], 1);
}

__global__ __launch_bounds__(256) void k_hist(const int* __restrict__ et, int E, int* __restrict__ hist) {
  __shared__ int h[R_];
  for (int i = threadIdx.x; i < R_; i += 256) h[i] = 0;
  __syncthreads();
  int base = blockIdx.x * 4096;
  for (int j = 0; j < 16; j++) {
    int i = base + j * 256 + threadIdx.x;
    if (i < E) atomicAdd(&h[et[i]], 1);
  }
  __syncthreads();
  for (int i = threadIdx.x; i < R_; i += 256) { int v = h[i]; if (v) atomicAdd(&hist[i], v); }
}

// parallel relation scan with TE-padding (1 block, 256 threads)
__global__ __launch_bounds__(256) void k_scanRel(const int* __restrict__ hist,
                                                 int* __restrict__ padOff, int* __restrict__ cursor) {
  __shared__ int s[256];
  int tid = threadIdx.x;
  int v = (tid < R_) ? ((hist[tid] + TE - 1) / TE) * TE : 0;
  s[tid] = v;
  __syncthreads();
  for (int off = 1; off < 256; off <<= 1) {
    int t = (tid >= off) ? s[tid - off] : 0;
    __syncthreads();
    s[tid] += t;
    __syncthreads();
  }
  if (tid < R_) { int e = s[tid] - v; padOff[tid] = e; cursor[tid] = e; }
  if (tid == R_ - 1) padOff[R_] = s[tid];
}

__global__ __launch_bounds__(256) void k_scatter(const int* __restrict__ src, const int* __restrict__ dst,
                                                 const int* __restrict__ et, int E,
                                                 const int* __restrict__ counts, int* __restrict__ cursor,
                                                 int* __restrict__ srcS, int* __restrict__ dstS,
                                                 float* __restrict__ normS) {
  __shared__ int h[R_];
  __shared__ int gb[R_];
  for (int i = threadIdx.x; i < R_; i += 256) h[i] = 0;
  __syncthreads();
  int base = blockIdx.x * 4096;
  int lrank[16];
#pragma unroll
  for (int j = 0; j < 16; j++) {
    int i = base + j * 256 + threadIdx.x;
    lrank[j] = (i < E) ? atomicAdd(&h[et[i]], 1) : 0;
  }
  __syncthreads();
  for (int i = threadIdx.x; i < R_; i += 256) { int v = h[i]; gb[i] = v ? atomicAdd(&cursor[i], v) : 0; }
  __syncthreads();
#pragma unroll
  for (int j = 0; j < 16; j++) {
    int i = base + j * 256 + threadIdx.x;
    if (i < E) {
      int r = et[i], d = dst[i];
      int pos = gb[r] + lrank[j];
      srcS[pos] = src[i];
      dstS[pos] = d;
      int c = counts[d * R_ + r];
      normS[pos] = 1.0f / (float)(c > 1 ? c : 1);
    }
  }
}

__global__ __launch_bounds__(256) void k_tileRel(const int* __restrict__ padOff, int* __restrict__ tileRel, int uT) {
  int t = blockIdx.x * 256 + threadIdx.x;
  if (t >= uT) return;
  int base = t * TE;
  if (base >= padOff[R_]) { tileRel[t] = 0; return; }
  int lo = 0, hi = R_ - 1;
  while (lo < hi) { int mid = (lo + hi + 1) >> 1; if (padOff[mid] <= base) lo = mid; else hi = mid - 1; }
  tileRel[t] = lo;
}

// ---------------- dst-sort: parallel 3-kernel scan ----------------

__global__ __launch_bounds__(256) void k_countDst(const int* __restrict__ dst, int E, int* __restrict__ deg) {
  int i = blockIdx.x * 256 + threadIdx.x;
  if (i < E) atomicAdd(&deg[dst[i]], 1);
}

__global__ __launch_bounds__(256) void k_degPart(const int* __restrict__ deg, int* __restrict__ blkSum) {
  __shared__ int ws_[4];
  int i = blockIdx.x * 256 + threadIdx.x;
  int v = (i < N_) ? deg[i] : 0;
#pragma unroll
  for (int off = 32; off >= 1; off >>= 1) v += __shfl_down(v, off);
  if ((threadIdx.x & 63) == 0) ws_[threadIdx.x >> 6] = v;
  __syncthreads();
  if (threadIdx.x == 0) blkSum[blockIdx.x] = ws_[0] + ws_[1] + ws_[2] + ws_[3];
}

__global__ __launch_bounds__(512) void k_scanBlk(const int* __restrict__ blkSum, int* __restrict__ blkOff, int nblk) {
  __shared__ int s[512];
  int tid = threadIdx.x;
  int v = (tid < nblk) ? blkSum[tid] : 0;
  s[tid] = v;
  __syncthreads();
  for (int off = 1; off < 512; off <<= 1) {
    int t = (tid >= off) ? s[tid - off] : 0;
    __syncthreads();
    s[tid] += t;
    __syncthreads();
  }
  if (tid < nblk) blkOff[tid] = s[tid] - v;   // exclusive
}

__global__ __launch_bounds__(256) void k_writeOff(const int* __restrict__ deg, const int* __restrict__ blkOff,
                                                  int* __restrict__ dstOff, int* __restrict__ cur) {
  __shared__ int s[256];
  int i = blockIdx.x * 256 + threadIdx.x;
  int tid = threadIdx.x;
  int v = (i < N_) ? deg[i] : 0;
  s[tid] = v;
  __syncthreads();
  for (int off = 1; off < 256; off <<= 1) {
    int t = (tid >= off) ? s[tid - off] : 0;
    __syncthreads();
    s[tid] += t;
    __syncthreads();
  }
  int e = blkOff[blockIdx.x] + s[tid] - v;    // global exclusive prefix
  if (i < N_) { dstOff[i] = e; cur[i] = e; }
  else if (i == N_) dstOff[N_] = e;
}

__global__ __launch_bounds__(256) void k_scatterDst(const int* __restrict__ dstS, const float* __restrict__ normS,
                                                    const int* __restrict__ padOff, int* __restrict__ cur,
                                                    int* __restrict__ posbuf, int plo, int phi) {
  int p = plo + blockIdx.x * 256 + threadIdx.x;
  if (p >= phi || p >= padOff[R_]) return;
  if (normS[p] <= 0.f) return;
  int d = dstS[p];
  int j = atomicAdd(&cur[d], 1);
  posbuf[j] = p;
}

__global__ __launch_bounds__(256) void k_copyBound(const int* __restrict__ cur, int* __restrict__ bnd) {
  int d = blockIdx.x * 256 + threadIdx.x;
  if (d < N_) bnd[d] = cur[d];
}

// ---------------- W_r = sum_b comp[r,b]*basis[b]; pack to B-fragment order ----------------

__global__ __launch_bounds__(256) void k_computeW(const float* __restrict__ comp, const float* __restrict__ basis,
                                                  float* __restrict__ W) {
  __shared__ float c[B_];
  int r = blockIdx.x >> 6;
  int chunk = blockIdx.x & 63;
  if (threadIdx.x < B_) c[threadIdx.x] = comp[r * B_ + threadIdx.x];
  __syncthreads();
  int ij = chunk * 256 + threadIdx.x;
  float acc = 0.f;
#pragma unroll 10
  for (int b = 0; b < B_; b++) acc += c[b] * basis[b * (D_ * D_) + ij];
  W[r * (D_ * D_) + ij] = acc;
}

// pack: Wpack[r][ks][cg][lane][j] = bf16(W[r][ks*32+(lane>>4)*8+j][cg*16+(lane&15)])
__global__ __launch_bounds__(256) void k_packW(const float* __restrict__ W, ushort* __restrict__ Wpack) {
  int r = blockIdx.x;
  const float* Wr = W + (size_t)r * (D_ * D_);
  ushort* out = Wpack + (size_t)r * (D_ * D_);
  for (int i = threadIdx.x; i < D_ * D_; i += 256) {
    int j = i & 7, l = (i >> 3) & 63, cg = (i >> 9) & 7, ks = i >> 12;
    int k = ks * 32 + (l >> 4) * 8 + j;
    int n = cg * 16 + (l & 15);
    out[i] = f2bf(Wr[k * D_ + n]);
  }
}

__global__ __launch_bounds__(256) void k_cast(const float* __restrict__ x, ushort* __restrict__ xb, int n8) {
  int i = blockIdx.x * 256 + threadIdx.x;
  if (i >= n8) return;
  const float4* xp = (const float4*)(x + (size_t)i * 8);
  float4 a = xp[0], b = xp[1];
  uint4 pk;
  pk.x = (uint)f2bf(a.x) | ((uint)f2bf(a.y) << 16);
  pk.y = (uint)f2bf(a.z) | ((uint)f2bf(a.w) << 16);
  pk.z = (uint)f2bf(b.x) | ((uint)f2bf(b.y) << 16);
  pk.w = (uint)f2bf(b.z) | ((uint)f2bf(b.w) << 16);
  *(uint4*)(xb + (size_t)i * 8) = pk;
}

// ---------------- fp32 tile core (root GEMM only) ----------------

__device__ __forceinline__ void tile_mm(const float (*xs)[D_], const float* __restrict__ Wg,
                                        int tx, int ty, float acc[8][4]) {
#pragma unroll
  for (int e = 0; e < 8; e++) { acc[e][0] = 0.f; acc[e][1] = 0.f; acc[e][2] = 0.f; acc[e][3] = 0.f; }
  for (int k = 0; k < D_; k += 4) {
    float w[4][4];
#pragma unroll
    for (int kk = 0; kk < 4; kk++) {
      float4 t = *(const float4*)(Wg + (k + kk) * D_ + 4 * tx);
      w[kk][0] = t.x; w[kk][1] = t.y; w[kk][2] = t.z; w[kk][3] = t.w;
    }
#pragma unroll
    for (int e = 0; e < 8; e++) {
      float4 xv = *(const float4*)&xs[ty + 8 * e][k];
#pragma unroll
      for (int cc = 0; cc < 4; cc++)
        acc[e][cc] += xv.x * w[0][cc] + xv.y * w[1][cc] + xv.z * w[2][cc] + xv.w * w[3][cc];
    }
  }
}

__global__ __launch_bounds__(256) void k_root(const float* __restrict__ x, const float* __restrict__ root,
                                              const float* __restrict__ bias, float* __restrict__ y) {
  __shared__ float xs[TE][D_];
  int row0 = blockIdx.x * TE;
  for (int idx = threadIdx.x; idx < TE * D_; idx += 256) {
    int rr = idx >> 7, cc = idx & 127;
    int gr = row0 + rr;
    xs[rr][cc] = (gr < N_) ? x[(size_t)gr * D_ + cc] : 0.f;
  }
  __syncthreads();
  int tx = threadIdx.x & 31, ty = threadIdx.x >> 5;
  float acc[8][4];
  tile_mm(xs, root, tx, ty, acc);
  float4 b4 = *(const float4*)(bias + 4 * tx);
#pragma unroll
  for (int e = 0; e < 8; e++) {
    int gr = row0 + ty + 8 * e;
    if (gr < N_) {
      float4 o;
      o.x = acc[e][0] + b4.x; o.y = acc[e][1] + b4.y;
      o.z = acc[e][2] + b4.z; o.w = acc[e][3] + b4.w;
      *(float4*)(y + (size_t)gr * D_ + 4 * tx) = o;
    }
  }
}

// ---------------- phase A: MFMA edge messages ----------------

__global__ __launch_bounds__(256) void k_edges_mfma(
    const ushort* __restrict__ xb, const ushort* __restrict__ Wpack,
    const int* __restrict__ srcS, const float* __restrict__ normS,
    const int* __restrict__ tileRel, const int* __restrict__ padOff,
    ushort* __restrict__ msg, int tile0, int tile1) {
  int padTot = padOff[R_];
  int tstart = tile0 + blockIdx.x * G_;
  if (tstart >= tile1 || tstart * TE >= padTot) return;
  int tend = tstart + G_; if (tend > tile1) tend = tile1;
  int w = threadIdx.x >> 6, l = threadIdx.x & 63;
  int q = l >> 4, tx = l & 15;
  int curRel = -1;
  s8b b[4][8];
  for (int tile = tstart; tile < tend; ++tile) {
    int base = tile * TE;
    if (base >= padTot) break;
    int rel = tileRel[tile];
    if (rel != curRel) {
      curRel = rel;
      const s8b* wp = (const s8b*)(Wpack + (size_t)rel * (D_ * D_));
#pragma unroll
      for (int ks = 0; ks < 4; ++ks)
#pragma unroll
        for (int cg = 0; cg < 8; ++cg)
          b[ks][cg] = wp[(ks * 8 + cg) * 64 + l];
    }
    int rowA = base + 16 * w + tx;
    int srcRow = srcS[rowA];
    const s8b* xr = (const s8b*)(xb + (size_t)srcRow * D_);
    s8b a0 = xr[q], a1 = xr[4 + q], a2 = xr[8 + q], a3 = xr[12 + q];
    f32x4 acc[8];
#pragma unroll
    for (int cg = 0; cg < 8; ++cg) acc[cg] = (f32x4){0.f, 0.f, 0.f, 0.f};
#pragma unroll
    for (int cg = 0; cg < 8; ++cg) {
      acc[cg] = __builtin_amdgcn_mfma_f32_16x16x32_bf16(a0, b[0][cg], acc[cg], 0, 0, 0);
      acc[cg] = __builtin_amdgcn_mfma_f32_16x16x32_bf16(a1, b[1][cg], acc[cg], 0, 0, 0);
      acc[cg] = __builtin_amdgcn_mfma_f32_16x16x32_bf16(a2, b[2][cg], acc[cg], 0, 0, 0);
      acc[cg] = __builtin_amdgcn_mfma_f32_16x16x32_bf16(a3, b[3][cg], acc[cg], 0, 0, 0);
    }
    float nv[4];
#pragma unroll
    for (int r = 0; r < 4; ++r) nv[r] = normS[base + 16 * w + 4 * q + r];
    size_t rowBase = (size_t)(tile - tile0) * TE + 16 * w;
#pragma unroll
    for (int cg = 0; cg < 8; ++cg) {
      int col = cg * 16 + tx;
#pragma unroll
      for (int r = 0; r < 4; ++r) {
        float v = acc[cg][r] * nv[r];
        msg[(rowBase + 4 * q + r) * D_ + col] = f2bf(v);
      }
    }
  }
}

// ---------------- phase B: wave-per-dst aggregation ----------------

__global__ __launch_bounds__(256) void k_agg2(const ushort* __restrict__ msg, const int* __restrict__ posbuf,
                                              const int* __restrict__ jlo, const int* __restrict__ jhi,
                                              float* __restrict__ y, int plo, int final_) {
  int d = blockIdx.x * 4 + (threadIdx.x >> 6);
  if (d >= N_) return;
  int l = threadIdx.x & 63, sub = l >> 4, tx = l & 15;
  int s0 = jlo[d], s1 = jhi[d];
  float acc[8];
#pragma unroll
  for (int i = 0; i < 8; ++i) acc[i] = 0.f;
  for (int j = s0 + sub; j < s1; j += 4) {
    int p = posbuf[j];
    uint4 mv = *(const uint4*)(msg + (((size_t)(p - plo)) << 7) + (tx << 3));
    acc[0] += bf2f((ushort)mv.x); acc[1] += bf2f((ushort)(mv.x >> 16));
    acc[2] += bf2f((ushort)mv.y); acc[3] += bf2f((ushort)(mv.y >> 16));
    acc[4] += bf2f((ushort)mv.z); acc[5] += bf2f((ushort)(mv.z >> 16));
    acc[6] += bf2f((ushort)mv.w); acc[7] += bf2f((ushort)(mv.w >> 16));
  }
#pragma unroll
  for (int i = 0; i < 8; ++i) {
    acc[i] += __shfl_xor(acc[i], 16);
    acc[i] += __shfl_xor(acc[i], 32);
  }
  if (sub == 0) {
    float* yp = y + (((size_t)d) << 7) + (tx << 3);
    float4 y0 = *(float4*)yp, y1 = *(float4*)(yp + 4);
    y0.x += acc[0]; y0.y += acc[1]; y0.z += acc[2]; y0.w += acc[3];
    y1.x += acc[4]; y1.y += acc[5]; y1.z += acc[6]; y1.w += acc[7];
    if (final_) {
      y0.x = fmaxf(y0.x, 0.f); y0.y = fmaxf(y0.y, 0.f); y0.z = fmaxf(y0.z, 0.f); y0.w = fmaxf(y0.w, 0.f);
      y1.x = fmaxf(y1.x, 0.f); y1.y = fmaxf(y1.y, 0.f); y1.z = fmaxf(y1.z, 0.f); y1.w = fmaxf(y1.w, 0.f);
    }
    *(float4*)yp = y0; *(float4*)(yp + 4) = y1;
  }
}

// ---------------- launch ----------------

extern "C" void kernel_launch(void* const* d_in, const int* in_sizes, int n_in,
                              void* d_out, int out_size, void* d_ws, size_t ws_size,
                              hipStream_t stream) {
  const float* entity = (const float*)d_in[0];
  const float* comp   = (const float*)d_in[1];
  const float* basis  = (const float*)d_in[2];
  const float* root   = (const float*)d_in[3];
  const float* bias   = (const float*)d_in[4];
  const int*   eidx   = (const int*)d_in[5];
  const int*   etype  = (const int*)d_in[6];
  const int E = in_sizes[6];
  const int* src = eidx;
  const int* dst = eidx + E;

  char* ws = (char*)d_ws;
  const size_t Epad = (size_t)E + (size_t)R_ * TE;
  const int uTiles = (E + TE - 1) / TE + R_;
  const int NBLK = (N_ + 1 + 255) / 256;
  auto al = [](size_t x) { return (x + 255) & ~(size_t)255; };

  size_t o_Wpack  = 0;
  size_t o_srcS   = al(o_Wpack + (size_t)R_ * D_ * D_ * 2);
  size_t o_normS  = al(o_srcS + Epad * 4);
  size_t o_posbuf = al(o_normS + Epad * 4);
  size_t o_degDst = al(o_posbuf + (size_t)E * 4);
  size_t o_dstOff = al(o_degDst + (size_t)N_ * 4);
  size_t o_cursD  = al(o_dstOff + (size_t)(N_ + 8) * 4);
  size_t o_bounds = al(o_cursD + (size_t)N_ * 4);
  size_t o_tileRel= al(o_bounds + (size_t)MAXC * N_ * 4);
  size_t o_small  = al(o_tileRel + (size_t)uTiles * 4);
  size_t o_x1     = al(o_small + 8192);
  size_t o_xb     = al(o_x1 + (size_t)N_ * D_ * 4);
  size_t o_msg    = al(o_xb + (size_t)N_ * D_ * 2);

  // aliases inside the msg region (all dead before first msg write):
  size_t o_counts = o_msg;                                   // N*R*4 = 80MB, dead after k_scatter
  size_t o_dstS   = al(o_counts + (size_t)N_ * R_ * 4);      // dead after k_scatterDst passes
  size_t o_Wf     = o_msg;                                   // per-layer, dead after k_packW

  ushort* Wpack  = (ushort*)(ws + o_Wpack);
  int*    srcS   = (int*)(ws + o_srcS);
  float*  normS  = (float*)(ws + o_normS);
  int*    posbuf = (int*)(ws + o_posbuf);
  int*    degDst = (int*)(ws + o_degDst);
  int*    dstOff = (int*)(ws + o_dstOff);
  int*    cursD  = (int*)(ws + o_cursD);
  int*    bounds = (int*)(ws + o_bounds);
  int*    tileRel= (int*)(ws + o_tileRel);
  int*    hist   = (int*)(ws + o_small);
  int*    padOff = hist + 256;
  int*    cursor = hist + 512;
  int*    blkSum = hist + 768;
  int*    blkOff = hist + 1280;
  float*  x1     = (float*)(ws + o_x1);
  ushort* xb     = (ushort*)(ws + o_xb);
  int*    counts = (int*)(ws + o_counts);
  int*    dstS   = (int*)(ws + o_dstS);
  float*  Wf     = (float*)(ws + o_Wf);
  ushort* msg    = (ushort*)(ws + o_msg);

  // zero: srcS+normS (padding), degDst, small, counts
  hipMemsetAsync(ws + o_srcS, 0, o_posbuf - o_srcS, stream);
  hipMemsetAsync(ws + o_degDst, 0, (size_t)N_ * 4, stream);
  hipMemsetAsync(ws + o_small, 0, 8192, stream);
  hipMemsetAsync(ws + o_counts, 0, (size_t)N_ * R_ * 4, stream);

  int gE = (E + 255) / 256;
  int gH = (E + 4095) / 4096;
  k_count<<<gE, 256, 0, stream>>>(dst, etype, E, counts);
  k_hist<<<gH, 256, 0, stream>>>(etype, E, hist);
  k_scanRel<<<1, 256, 0, stream>>>(hist, padOff, cursor);
  k_scatter<<<gH, 256, 0, stream>>>(src, dst, etype, E, counts, cursor, srcS, dstS, normS);
  k_tileRel<<<(uTiles + 255) / 256, 256, 0, stream>>>(padOff, tileRel, uTiles);
  k_countDst<<<gE, 256, 0, stream>>>(dst, E, degDst);
  k_degPart<<<NBLK, 256, 0, stream>>>(degDst, blkSum);
  k_scanBlk<<<1, 512, 0, stream>>>(blkSum, blkOff, NBLK);
  k_writeOff<<<NBLK, 256, 0, stream>>>(degDst, blkOff, dstOff, cursD);

  // chunking from ws capacity
  size_t cap = (ws_size > o_msg + 16384) ? (ws_size - o_msg) : (size_t)16384;
  size_t tileBytes = (size_t)TE * D_ * 2;
  long long maxT = (long long)(cap / tileBytes);
  if (maxT < 1) maxT = 1;
  int nch = (int)((uTiles + maxT - 1) / maxT);
  if (nch < 1) nch = 1;
  if (nch > MAXC) nch = MAXC;
  int chunkTiles = (uTiles + nch - 1) / nch;
  nch = (uTiles + chunkTiles - 1) / chunkTiles;

  // chunk-major posbuf: scatter per chunk, snapshot cursors
  for (int c = 0; c < nch; c++) {
    int plo = c * chunkTiles * TE;
    int phi = (c + 1) * chunkTiles * TE; if (phi > uTiles * TE) phi = uTiles * TE;
    int gS = (phi - plo + 255) / 256;
    if (gS > 0)
      k_scatterDst<<<gS, 256, 0, stream>>>(dstS, normS, padOff, cursD, posbuf, plo, phi);
    k_copyBound<<<(N_ + 255) / 256, 256, 0, stream>>>(cursD, bounds + (size_t)c * N_);
  }

  int gRoot = (N_ + TE - 1) / TE;
  int gAgg = (N_ + 3) / 4;
  for (int l = 0; l < 2; l++) {
    const float* xin = l ? x1 : entity;
    float* yout = l ? (float*)d_out : x1;
    k_computeW<<<R_ * 64, 256, 0, stream>>>(comp + l * R_ * B_, basis + (size_t)l * B_ * D_ * D_, Wf);
    k_packW<<<R_, 256, 0, stream>>>(Wf, Wpack);
    k_cast<<<(N_ * D_ / 8 + 255) / 256, 256, 0, stream>>>(xin, xb, N_ * D_ / 8);
    k_root<<<gRoot, 256, 0, stream>>>(xin, root + l * D_ * D_, bias + l * D_, yout);
    for (int c = 0; c < nch; c++) {
      int t0 = c * chunkTiles;
      int t1 = t0 + chunkTiles; if (t1 > uTiles) t1 = uTiles;
      int gB = (t1 - t0 + G_ - 1) / G_;
      k_edges_mfma<<<gB, 256, 0, stream>>>(xb, Wpack, srcS, normS, tileRel, padOff, msg, t0, t1);
      const int* jlo = (c == 0) ? dstOff : bounds + (size_t)(c - 1) * N_;
      const int* jhi = bounds + (size_t)c * N_;
      k_agg2<<<gAgg, 256, 0, stream>>>(msg, posbuf, jlo, jhi, yout, t0 * TE, c == nch - 1);
    }
  }
}

// Round 5
// 1252.410 us; speedup vs baseline: 4.6690x; 1.0485x over previous
//
#include <hip/hip_runtime.h>
#include <hip/hip_bf16.h>
#include <stdint.h>

#define D_ 128
#define R_ 200
#define B_ 50
#define N_ 100000
#define TE 64
#define G_ 8
#define MAXC 8

typedef __attribute__((ext_vector_type(8))) short s8b;
typedef __attribute__((ext_vector_type(4))) float f32x4;

// ---------------- helpers ----------------

__device__ __forceinline__ ushort f2bf(float f) {   // RTN-even fp32 -> bf16
  uint u = __float_as_uint(f);
  return (ushort)((u + 0x7fffu + ((u >> 16) & 1u)) >> 16);
}
__device__ __forceinline__ float bf2f(ushort u) {
  return __uint_as_float(((uint)u) << 16);
}

// ---------------- counting / sorting machinery ----------------

__global__ __launch_bounds__(256) void k_hist(const int* __restrict__ et, int E, int* __restrict__ hist) {
  __shared__ int h[R_];
  for (int i = threadIdx.x; i < R_; i += 256) h[i] = 0;
  __syncthreads();
  int base = blockIdx.x * 4096;
  for (int j = 0; j < 16; j++) {
    int i = base + j * 256 + threadIdx.x;
    if (i < E) atomicAdd(&h[et[i]], 1);
  }
  __syncthreads();
  for (int i = threadIdx.x; i < R_; i += 256) { int v = h[i]; if (v) atomicAdd(&hist[i], v); }
}

// parallel relation scan with TE-padding (1 block, 256 threads)
__global__ __launch_bounds__(256) void k_scanRel(const int* __restrict__ hist,
                                                 int* __restrict__ padOff, int* __restrict__ cursor) {
  __shared__ int s[256];
  int tid = threadIdx.x;
  int v = (tid < R_) ? ((hist[tid] + TE - 1) / TE) * TE : 0;
  s[tid] = v;
  __syncthreads();
  for (int off = 1; off < 256; off <<= 1) {
    int t = (tid >= off) ? s[tid - off] : 0;
    __syncthreads();
    s[tid] += t;
    __syncthreads();
  }
  if (tid < R_) { int e = s[tid] - v; padOff[tid] = e; cursor[tid] = e; }
  if (tid == R_ - 1) padOff[R_] = s[tid];
}

__global__ __launch_bounds__(256) void k_scatter(const int* __restrict__ src, const int* __restrict__ dst,
                                                 const int* __restrict__ et, int E,
                                                 int* __restrict__ cursor,
                                                 int* __restrict__ srcS, int* __restrict__ dstS) {
  __shared__ int h[R_];
  __shared__ int gb[R_];
  for (int i = threadIdx.x; i < R_; i += 256) h[i] = 0;
  __syncthreads();
  int base = blockIdx.x * 4096;
  int lrank[16];
#pragma unroll
  for (int j = 0; j < 16; j++) {
    int i = base + j * 256 + threadIdx.x;
    lrank[j] = (i < E) ? atomicAdd(&h[et[i]], 1) : 0;
  }
  __syncthreads();
  for (int i = threadIdx.x; i < R_; i += 256) { int v = h[i]; gb[i] = v ? atomicAdd(&cursor[i], v) : 0; }
  __syncthreads();
#pragma unroll
  for (int j = 0; j < 16; j++) {
    int i = base + j * 256 + threadIdx.x;
    if (i < E) {
      int r = et[i];
      int pos = gb[r] + lrank[j];
      srcS[pos] = src[i];
      dstS[pos] = dst[i];
    }
  }
}

__global__ __launch_bounds__(256) void k_tileRel(const int* __restrict__ padOff, int* __restrict__ tileRel, int uT) {
  int t = blockIdx.x * 256 + threadIdx.x;
  if (t >= uT) return;
  int base = t * TE;
  if (base >= padOff[R_]) { tileRel[t] = 0; return; }
  int lo = 0, hi = R_ - 1;
  while (lo < hi) { int mid = (lo + hi + 1) >> 1; if (padOff[mid] <= base) lo = mid; else hi = mid - 1; }
  tileRel[t] = lo;
}

// ---------------- dst-sort: parallel 3-kernel scan ----------------

__global__ __launch_bounds__(256) void k_countDst(const int* __restrict__ dst, int E, int* __restrict__ deg) {
  int i = blockIdx.x * 256 + threadIdx.x;
  if (i < E) atomicAdd(&deg[dst[i]], 1);
}

__global__ __launch_bounds__(256) void k_degPart(const int* __restrict__ deg, int* __restrict__ blkSum) {
  __shared__ int ws_[4];
  int i = blockIdx.x * 256 + threadIdx.x;
  int v = (i < N_) ? deg[i] : 0;
#pragma unroll
  for (int off = 32; off >= 1; off >>= 1) v += __shfl_down(v, off);
  if ((threadIdx.x & 63) == 0) ws_[threadIdx.x >> 6] = v;
  __syncthreads();
  if (threadIdx.x == 0) blkSum[blockIdx.x] = ws_[0] + ws_[1] + ws_[2] + ws_[3];
}

__global__ __launch_bounds__(512) void k_scanBlk(const int* __restrict__ blkSum, int* __restrict__ blkOff, int nblk) {
  __shared__ int s[512];
  int tid = threadIdx.x;
  int v = (tid < nblk) ? blkSum[tid] : 0;
  s[tid] = v;
  __syncthreads();
  for (int off = 1; off < 512; off <<= 1) {
    int t = (tid >= off) ? s[tid - off] : 0;
    __syncthreads();
    s[tid] += t;
    __syncthreads();
  }
  if (tid < nblk) blkOff[tid] = s[tid] - v;   // exclusive
}

__global__ __launch_bounds__(256) void k_writeOff(const int* __restrict__ deg, const int* __restrict__ blkOff,
                                                  int* __restrict__ dstOff, int* __restrict__ cur) {
  __shared__ int s[256];
  int i = blockIdx.x * 256 + threadIdx.x;
  int tid = threadIdx.x;
  int v = (i < N_) ? deg[i] : 0;
  s[tid] = v;
  __syncthreads();
  for (int off = 1; off < 256; off <<= 1) {
    int t = (tid >= off) ? s[tid - off] : 0;
    __syncthreads();
    s[tid] += t;
    __syncthreads();
  }
  int e = blkOff[blockIdx.x] + s[tid] - v;    // global exclusive prefix
  if (i < N_) { dstOff[i] = e; cur[i] = e; }
  else if (i == N_) dstOff[N_] = e;
}

__global__ __launch_bounds__(256) void k_scatterDst(const int* __restrict__ dstS,
                                                    const int* __restrict__ padOff, int* __restrict__ cur,
                                                    int* __restrict__ posbuf, int plo, int phi) {
  int p = plo + blockIdx.x * 256 + threadIdx.x;
  if (p >= phi || p >= padOff[R_]) return;
  int d = dstS[p];
  if (d < 0) return;                 // padding slot
  int j = atomicAdd(&cur[d], 1);
  posbuf[j] = p;
}

__global__ __launch_bounds__(256) void k_copyBound(const int* __restrict__ cur, int* __restrict__ bnd) {
  int d = blockIdx.x * 256 + threadIdx.x;
  if (d < N_) bnd[d] = cur[d];
}

// ---------------- per-edge mean-norm from dst-sorted segments ----------------
// normS[p] = 1 / #{edges in dst-segment with same relation}; rel(p)=tileRel[p>>6]

__global__ __launch_bounds__(256) void k_norm(const int* __restrict__ posbuf, const int* __restrict__ dstOff,
                                              const int* __restrict__ tileRel, float* __restrict__ normS) {
  __shared__ int rels[4][128];
  int d = blockIdx.x * 4 + (threadIdx.x >> 6);
  int sub = threadIdx.x >> 6;
  int l = threadIdx.x & 63;
  int s0 = 0, deg = 0;
  if (d < N_) { s0 = dstOff[d]; deg = dstOff[d + 1] - s0; }
  int cap = deg < 128 ? deg : 128;
  int myp[4]; int myr[4];   // up to 4*64=256 edges per lane-set before fallback
  for (int j = l, t = 0; j < cap; j += 64, ++t) {
    int p = posbuf[s0 + j];
    int r = tileRel[p >> 6];
    rels[sub][j] = r;
    if (t < 4) { myp[t] = p; myr[t] = r; }
  }
  __syncthreads();
  if (d >= N_) return;
  for (int j = l, t = 0; j < deg; j += 64, ++t) {
    int p, r;
    if (j < 128 && t < 4) { p = myp[t]; r = myr[t]; }
    else { p = posbuf[s0 + j]; r = tileRel[p >> 6]; }
    int cnt = 0;
    for (int k = 0; k < deg; k++) {
      int rk = (k < 128) ? rels[sub][k] : tileRel[posbuf[s0 + k] >> 6];
      cnt += (rk == r) ? 1 : 0;
    }
    normS[p] = 1.0f / (float)(cnt > 0 ? cnt : 1);
  }
}

// ---------------- W_r = sum_b comp[r,b]*basis[b]; pack to B-fragment order ----------------

__global__ __launch_bounds__(256) void k_computeW(const float* __restrict__ comp, const float* __restrict__ basis,
                                                  float* __restrict__ W) {
  __shared__ float c[B_];
  int r = blockIdx.x >> 6;
  int chunk = blockIdx.x & 63;
  if (threadIdx.x < B_) c[threadIdx.x] = comp[r * B_ + threadIdx.x];
  __syncthreads();
  int ij = chunk * 256 + threadIdx.x;
  float acc = 0.f;
#pragma unroll 10
  for (int b = 0; b < B_; b++) acc += c[b] * basis[b * (D_ * D_) + ij];
  W[r * (D_ * D_) + ij] = acc;
}

// pack: Wpack[r][ks][cg][lane][j] = bf16(W[r][ks*32+(lane>>4)*8+j][cg*16+(lane&15)])
__global__ __launch_bounds__(256) void k_packW(const float* __restrict__ W, ushort* __restrict__ Wpack) {
  int r = blockIdx.x;
  const float* Wr = W + (size_t)r * (D_ * D_);
  ushort* out = Wpack + (size_t)r * (D_ * D_);
  for (int i = threadIdx.x; i < D_ * D_; i += 256) {
    int j = i & 7, l = (i >> 3) & 63, cg = (i >> 9) & 7, ks = i >> 12;
    int k = ks * 32 + (l >> 4) * 8 + j;
    int n = cg * 16 + (l & 15);
    out[i] = f2bf(Wr[k * D_ + n]);
  }
}

__global__ __launch_bounds__(256) void k_cast(const float* __restrict__ x, ushort* __restrict__ xb, int n8) {
  int i = blockIdx.x * 256 + threadIdx.x;
  if (i >= n8) return;
  const float4* xp = (const float4*)(x + (size_t)i * 8);
  float4 a = xp[0], b = xp[1];
  uint4 pk;
  pk.x = (uint)f2bf(a.x) | ((uint)f2bf(a.y) << 16);
  pk.y = (uint)f2bf(a.z) | ((uint)f2bf(a.w) << 16);
  pk.z = (uint)f2bf(b.x) | ((uint)f2bf(b.y) << 16);
  pk.w = (uint)f2bf(b.z) | ((uint)f2bf(b.w) << 16);
  *(uint4*)(xb + (size_t)i * 8) = pk;
}

// ---------------- fp32 tile core (root GEMM only) ----------------

__device__ __forceinline__ void tile_mm(const float (*xs)[D_], const float* __restrict__ Wg,
                                        int tx, int ty, float acc[8][4]) {
#pragma unroll
  for (int e = 0; e < 8; e++) { acc[e][0] = 0.f; acc[e][1] = 0.f; acc[e][2] = 0.f; acc[e][3] = 0.f; }
  for (int k = 0; k < D_; k += 4) {
    float w[4][4];
#pragma unroll
    for (int kk = 0; kk < 4; kk++) {
      float4 t = *(const float4*)(Wg + (k + kk) * D_ + 4 * tx);
      w[kk][0] = t.x; w[kk][1] = t.y; w[kk][2] = t.z; w[kk][3] = t.w;
    }
#pragma unroll
    for (int e = 0; e < 8; e++) {
      float4 xv = *(const float4*)&xs[ty + 8 * e][k];
#pragma unroll
      for (int cc = 0; cc < 4; cc++)
        acc[e][cc] += xv.x * w[0][cc] + xv.y * w[1][cc] + xv.z * w[2][cc] + xv.w * w[3][cc];
    }
  }
}

__global__ __launch_bounds__(256) void k_root(const float* __restrict__ x, const float* __restrict__ root,
                                              const float* __restrict__ bias, float* __restrict__ y) {
  __shared__ float xs[TE][D_];
  int row0 = blockIdx.x * TE;
  for (int idx = threadIdx.x; idx < TE * D_; idx += 256) {
    int rr = idx >> 7, cc = idx & 127;
    int gr = row0 + rr;
    xs[rr][cc] = (gr < N_) ? x[(size_t)gr * D_ + cc] : 0.f;
  }
  __syncthreads();
  int tx = threadIdx.x & 31, ty = threadIdx.x >> 5;
  float acc[8][4];
  tile_mm(xs, root, tx, ty, acc);
  float4 b4 = *(const float4*)(bias + 4 * tx);
#pragma unroll
  for (int e = 0; e < 8; e++) {
    int gr = row0 + ty + 8 * e;
    if (gr < N_) {
      float4 o;
      o.x = acc[e][0] + b4.x; o.y = acc[e][1] + b4.y;
      o.z = acc[e][2] + b4.z; o.w = acc[e][3] + b4.w;
      *(float4*)(y + (size_t)gr * D_ + 4 * tx) = o;
    }
  }
}

// ---------------- phase A: MFMA edge messages ----------------

__global__ __launch_bounds__(256) void k_edges_mfma(
    const ushort* __restrict__ xb, const ushort* __restrict__ Wpack,
    const int* __restrict__ srcS, const float* __restrict__ normS,
    const int* __restrict__ tileRel, const int* __restrict__ padOff,
    ushort* __restrict__ msg, int tile0, int tile1) {
  int padTot = padOff[R_];
  int tstart = tile0 + blockIdx.x * G_;
  if (tstart >= tile1 || tstart * TE >= padTot) return;
  int tend = tstart + G_; if (tend > tile1) tend = tile1;
  int w = threadIdx.x >> 6, l = threadIdx.x & 63;
  int q = l >> 4, tx = l & 15;
  int curRel = -1;
  s8b b[4][8];
  for (int tile = tstart; tile < tend; ++tile) {
    int base = tile * TE;
    if (base >= padTot) break;
    int rel = tileRel[tile];
    if (rel != curRel) {
      curRel = rel;
      const s8b* wp = (const s8b*)(Wpack + (size_t)rel * (D_ * D_));
#pragma unroll
      for (int ks = 0; ks < 4; ++ks)
#pragma unroll
        for (int cg = 0; cg < 8; ++cg)
          b[ks][cg] = wp[(ks * 8 + cg) * 64 + l];
    }
    int rowA = base + 16 * w + tx;
    int srcRow = srcS[rowA];
    const s8b* xr = (const s8b*)(xb + (size_t)srcRow * D_);
    s8b a0 = xr[q], a1 = xr[4 + q], a2 = xr[8 + q], a3 = xr[12 + q];
    f32x4 acc[8];
#pragma unroll
    for (int cg = 0; cg < 8; ++cg) acc[cg] = (f32x4){0.f, 0.f, 0.f, 0.f};
#pragma unroll
    for (int cg = 0; cg < 8; ++cg) {
      acc[cg] = __builtin_amdgcn_mfma_f32_16x16x32_bf16(a0, b[0][cg], acc[cg], 0, 0, 0);
      acc[cg] = __builtin_amdgcn_mfma_f32_16x16x32_bf16(a1, b[1][cg], acc[cg], 0, 0, 0);
      acc[cg] = __builtin_amdgcn_mfma_f32_16x16x32_bf16(a2, b[2][cg], acc[cg], 0, 0, 0);
      acc[cg] = __builtin_amdgcn_mfma_f32_16x16x32_bf16(a3, b[3][cg], acc[cg], 0, 0, 0);
    }
    float nv[4];
#pragma unroll
    for (int r = 0; r < 4; ++r) nv[r] = normS[base + 16 * w + 4 * q + r];
    size_t rowBase = (size_t)(tile - tile0) * TE + 16 * w;
#pragma unroll
    for (int cg = 0; cg < 8; ++cg) {
      int col = cg * 16 + tx;
#pragma unroll
      for (int r = 0; r < 4; ++r) {
        float v = acc[cg][r] * nv[r];
        msg[(rowBase + 4 * q + r) * D_ + col] = f2bf(v);
      }
    }
  }
}

// ---------------- phase B: wave-per-dst aggregation ----------------

__global__ __launch_bounds__(256) void k_agg2(const ushort* __restrict__ msg, const int* __restrict__ posbuf,
                                              const int* __restrict__ jlo, const int* __restrict__ jhi,
                                              float* __restrict__ y, int plo, int final_) {
  int d = blockIdx.x * 4 + (threadIdx.x >> 6);
  if (d >= N_) return;
  int l = threadIdx.x & 63, sub = l >> 4, tx = l & 15;
  int s0 = jlo[d], s1 = jhi[d];
  float acc[8];
#pragma unroll
  for (int i = 0; i < 8; ++i) acc[i] = 0.f;
  for (int j = s0 + sub; j < s1; j += 4) {
    int p = posbuf[j];
    uint4 mv = *(const uint4*)(msg + (((size_t)(p - plo)) << 7) + (tx << 3));
    acc[0] += bf2f((ushort)mv.x); acc[1] += bf2f((ushort)(mv.x >> 16));
    acc[2] += bf2f((ushort)mv.y); acc[3] += bf2f((ushort)(mv.y >> 16));
    acc[4] += bf2f((ushort)mv.z); acc[5] += bf2f((ushort)(mv.z >> 16));
    acc[6] += bf2f((ushort)mv.w); acc[7] += bf2f((ushort)(mv.w >> 16));
  }
#pragma unroll
  for (int i = 0; i < 8; ++i) {
    acc[i] += __shfl_xor(acc[i], 16);
    acc[i] += __shfl_xor(acc[i], 32);
  }
  if (sub == 0) {
    float* yp = y + (((size_t)d) << 7) + (tx << 3);
    float4 y0 = *(float4*)yp, y1 = *(float4*)(yp + 4);
    y0.x += acc[0]; y0.y += acc[1]; y0.z += acc[2]; y0.w += acc[3];
    y1.x += acc[4]; y1.y += acc[5]; y1.z += acc[6]; y1.w += acc[7];
    if (final_) {
      y0.x = fmaxf(y0.x, 0.f); y0.y = fmaxf(y0.y, 0.f); y0.z = fmaxf(y0.z, 0.f); y0.w = fmaxf(y0.w, 0.f);
      y1.x = fmaxf(y1.x, 0.f); y1.y = fmaxf(y1.y, 0.f); y1.z = fmaxf(y1.z, 0.f); y1.w = fmaxf(y1.w, 0.f);
    }
    *(float4*)yp = y0; *(float4*)(yp + 4) = y1;
  }
}

// ---------------- launch ----------------

extern "C" void kernel_launch(void* const* d_in, const int* in_sizes, int n_in,
                              void* d_out, int out_size, void* d_ws, size_t ws_size,
                              hipStream_t stream) {
  const float* entity = (const float*)d_in[0];
  const float* comp   = (const float*)d_in[1];
  const float* basis  = (const float*)d_in[2];
  const float* root   = (const float*)d_in[3];
  const float* bias   = (const float*)d_in[4];
  const int*   eidx   = (const int*)d_in[5];
  const int*   etype  = (const int*)d_in[6];
  const int E = in_sizes[6];
  const int* src = eidx;
  const int* dst = eidx + E;

  char* ws = (char*)d_ws;
  const size_t Epad = (size_t)E + (size_t)R_ * TE;
  const int uTiles = (E + TE - 1) / TE + R_;
  const int NBLK = (N_ + 1 + 255) / 256;
  auto al = [](size_t x) { return (x + 255) & ~(size_t)255; };

  size_t o_Wpack  = 0;
  size_t o_srcS   = al(o_Wpack + (size_t)R_ * D_ * D_ * 2);
  size_t o_normS  = al(o_srcS + Epad * 4);
  size_t o_posbuf = al(o_normS + Epad * 4);
  size_t o_degDst = al(o_posbuf + (size_t)E * 4);
  size_t o_dstOff = al(o_degDst + (size_t)N_ * 4);
  size_t o_cursD  = al(o_dstOff + (size_t)(N_ + 8) * 4);
  size_t o_bounds = al(o_cursD + (size_t)N_ * 4);
  size_t o_tileRel= al(o_bounds + (size_t)MAXC * N_ * 4);
  size_t o_small  = al(o_tileRel + (size_t)uTiles * 4);
  size_t o_x1     = al(o_small + 8192);
  size_t o_xb     = al(o_x1 + (size_t)N_ * D_ * 4);
  size_t o_msg    = al(o_xb + (size_t)N_ * D_ * 2);

  // aliases inside the msg region (all dead before first msg write):
  size_t o_dstS   = o_msg;          // Epad*4, dead after k_scatterDst passes
  size_t o_Wf     = al(o_msg + Epad * 4);  // per-layer, dead after k_packW (before msg writes)

  ushort* Wpack  = (ushort*)(ws + o_Wpack);
  int*    srcS   = (int*)(ws + o_srcS);
  float*  normS  = (float*)(ws + o_normS);
  int*    posbuf = (int*)(ws + o_posbuf);
  int*    degDst = (int*)(ws + o_degDst);
  int*    dstOff = (int*)(ws + o_dstOff);
  int*    cursD  = (int*)(ws + o_cursD);
  int*    bounds = (int*)(ws + o_bounds);
  int*    tileRel= (int*)(ws + o_tileRel);
  int*    hist   = (int*)(ws + o_small);
  int*    padOff = hist + 256;
  int*    cursor = hist + 512;
  int*    blkSum = hist + 768;
  int*    blkOff = hist + 1280;
  float*  x1     = (float*)(ws + o_x1);
  ushort* xb     = (ushort*)(ws + o_xb);
  int*    dstS   = (int*)(ws + o_dstS);
  float*  Wf     = (float*)(ws + o_Wf);
  ushort* msg    = (ushort*)(ws + o_msg);

  // zero: srcS (padding-safe gather), degDst, small; dstS = -1 (padding marker)
  hipMemsetAsync(ws + o_srcS, 0, Epad * 4, stream);
  hipMemsetAsync(ws + o_degDst, 0, (size_t)N_ * 4, stream);
  hipMemsetAsync(ws + o_small, 0, 8192, stream);
  hipMemsetAsync(ws + o_dstS, 0xFF, Epad * 4, stream);

  int gH = (E + 4095) / 4096;
  int gE = (E + 255) / 256;
  k_hist<<<gH, 256, 0, stream>>>(etype, E, hist);
  k_scanRel<<<1, 256, 0, stream>>>(hist, padOff, cursor);
  k_scatter<<<gH, 256, 0, stream>>>(src, dst, etype, E, cursor, srcS, dstS);
  k_tileRel<<<(uTiles + 255) / 256, 256, 0, stream>>>(padOff, tileRel, uTiles);
  k_countDst<<<gE, 256, 0, stream>>>(dst, E, degDst);
  k_degPart<<<NBLK, 256, 0, stream>>>(degDst, blkSum);
  k_scanBlk<<<1, 512, 0, stream>>>(blkSum, blkOff, NBLK);
  k_writeOff<<<NBLK, 256, 0, stream>>>(degDst, blkOff, dstOff, cursD);

  // chunking from ws capacity
  size_t cap = (ws_size > o_msg + 16384) ? (ws_size - o_msg) : (size_t)16384;
  size_t tileBytes = (size_t)TE * D_ * 2;
  long long maxT = (long long)(cap / tileBytes);
  if (maxT < 1) maxT = 1;
  int nch = (int)((uTiles + maxT - 1) / maxT);
  if (nch < 1) nch = 1;
  if (nch > MAXC) nch = MAXC;
  int chunkTiles = (uTiles + nch - 1) / nch;
  nch = (uTiles + chunkTiles - 1) / chunkTiles;

  // chunk-major posbuf: scatter per chunk, snapshot cursors
  for (int c = 0; c < nch; c++) {
    int plo = c * chunkTiles * TE;
    int phi = (c + 1) * chunkTiles * TE; if (phi > uTiles * TE) phi = uTiles * TE;
    int gS = (phi - plo + 255) / 256;
    if (gS > 0)
      k_scatterDst<<<gS, 256, 0, stream>>>(dstS, padOff, cursD, posbuf, plo, phi);
    k_copyBound<<<(N_ + 255) / 256, 256, 0, stream>>>(cursD, bounds + (size_t)c * N_);
  }

  // per-edge mean-norm from the dst-sorted segments (replaces the N*R counts table)
  k_norm<<<(N_ + 3) / 4, 256, 0, stream>>>(posbuf, dstOff, tileRel, normS);

  int gRoot = (N_ + TE - 1) / TE;
  int gAgg = (N_ + 3) / 4;
  for (int l = 0; l < 2; l++) {
    const float* xin = l ? x1 : entity;
    float* yout = l ? (float*)d_out : x1;
    k_computeW<<<R_ * 64, 256, 0, stream>>>(comp + l * R_ * B_, basis + (size_t)l * B_ * D_ * D_, Wf);
    k_packW<<<R_, 256, 0, stream>>>(Wf, Wpack);
    k_cast<<<(N_ * D_ / 8 + 255) / 256, 256, 0, stream>>>(xin, xb, N_ * D_ / 8);
    k_root<<<gRoot, 256, 0, stream>>>(xin, root + l * D_ * D_, bias + l * D_, yout);
    for (int c = 0; c < nch; c++) {
      int t0 = c * chunkTiles;
      int t1 = t0 + chunkTiles; if (t1 > uTiles) t1 = uTiles;
      int gB = (t1 - t0 + G_ - 1) / G_;
      k_edges_mfma<<<gB, 256, 0, stream>>>(xb, Wpack, srcS, normS, tileRel, padOff, msg, t0, t1);
      const int* jlo = (c == 0) ? dstOff : bounds + (size_t)(c - 1) * N_;
      const int* jhi = bounds + (size_t)c * N_;
      k_agg2<<<gAgg, 256, 0, stream>>>(msg, posbuf, jlo, jhi, yout, t0 * TE, c == nch - 1);
    }
  }
}

// Round 6
// 1172.380 us; speedup vs baseline: 4.9877x; 1.0683x over previous
//
#include <hip/hip_runtime.h>
#include <hip/hip_bf16.h>
#include <stdint.h>

#define D_ 128
#define R_ 200
#define B_ 50
#define N_ 100000
#define TE 64
#define G_ 8
#define RG_ 4
#define MAXC 8

typedef __attribute__((ext_vector_type(8))) short s8b;
typedef __attribute__((ext_vector_type(4))) float f32x4;

// ---------------- helpers ----------------

__device__ __forceinline__ ushort f2bf(float f) {   // RTN-even fp32 -> bf16
  uint u = __float_as_uint(f);
  return (ushort)((u + 0x7fffu + ((u >> 16) & 1u)) >> 16);
}
__device__ __forceinline__ float bf2f(ushort u) {
  return __uint_as_float(((uint)u) << 16);
}

// ---------------- counting / sorting machinery ----------------

__global__ __launch_bounds__(256) void k_hist(const int* __restrict__ et, int E, int* __restrict__ hist) {
  __shared__ int h[R_];
  for (int i = threadIdx.x; i < R_; i += 256) h[i] = 0;
  __syncthreads();
  int base = blockIdx.x * 4096;
  for (int j = 0; j < 16; j++) {
    int i = base + j * 256 + threadIdx.x;
    if (i < E) atomicAdd(&h[et[i]], 1);
  }
  __syncthreads();
  for (int i = threadIdx.x; i < R_; i += 256) { int v = h[i]; if (v) atomicAdd(&hist[i], v); }
}

// parallel relation scan with TE-padding (1 block, 256 threads)
__global__ __launch_bounds__(256) void k_scanRel(const int* __restrict__ hist,
                                                 int* __restrict__ padOff, int* __restrict__ cursor) {
  __shared__ int s[256];
  int tid = threadIdx.x;
  int v = (tid < R_) ? ((hist[tid] + TE - 1) / TE) * TE : 0;
  s[tid] = v;
  __syncthreads();
  for (int off = 1; off < 256; off <<= 1) {
    int t = (tid >= off) ? s[tid - off] : 0;
    __syncthreads();
    s[tid] += t;
    __syncthreads();
  }
  if (tid < R_) { int e = s[tid] - v; padOff[tid] = e; cursor[tid] = e; }
  if (tid == R_ - 1) padOff[R_] = s[tid];
}

__global__ __launch_bounds__(256) void k_scatter(const int* __restrict__ src, const int* __restrict__ dst,
                                                 const int* __restrict__ et, int E,
                                                 int* __restrict__ cursor,
                                                 int* __restrict__ srcS, int* __restrict__ dstS) {
  __shared__ int h[R_];
  __shared__ int gb[R_];
  for (int i = threadIdx.x; i < R_; i += 256) h[i] = 0;
  __syncthreads();
  int base = blockIdx.x * 4096;
  int lrank[16];
#pragma unroll
  for (int j = 0; j < 16; j++) {
    int i = base + j * 256 + threadIdx.x;
    lrank[j] = (i < E) ? atomicAdd(&h[et[i]], 1) : 0;
  }
  __syncthreads();
  for (int i = threadIdx.x; i < R_; i += 256) { int v = h[i]; gb[i] = v ? atomicAdd(&cursor[i], v) : 0; }
  __syncthreads();
#pragma unroll
  for (int j = 0; j < 16; j++) {
    int i = base + j * 256 + threadIdx.x;
    if (i < E) {
      int r = et[i];
      int pos = gb[r] + lrank[j];
      srcS[pos] = src[i];
      dstS[pos] = dst[i];
    }
  }
}

__global__ __launch_bounds__(256) void k_tileRel(const int* __restrict__ padOff, int* __restrict__ tileRel, int uT) {
  int t = blockIdx.x * 256 + threadIdx.x;
  if (t >= uT) return;
  int base = t * TE;
  if (base >= padOff[R_]) { tileRel[t] = 0; return; }
  int lo = 0, hi = R_ - 1;
  while (lo < hi) { int mid = (lo + hi + 1) >> 1; if (padOff[mid] <= base) lo = mid; else hi = mid - 1; }
  tileRel[t] = lo;
}

// ---------------- dst-sort: parallel 3-kernel scan ----------------

__global__ __launch_bounds__(256) void k_countDst(const int* __restrict__ dst, int E, int* __restrict__ deg) {
  int i = blockIdx.x * 256 + threadIdx.x;
  if (i < E) atomicAdd(&deg[dst[i]], 1);
}

__global__ __launch_bounds__(256) void k_degPart(const int* __restrict__ deg, int* __restrict__ blkSum) {
  __shared__ int ws_[4];
  int i = blockIdx.x * 256 + threadIdx.x;
  int v = (i < N_) ? deg[i] : 0;
#pragma unroll
  for (int off = 32; off >= 1; off >>= 1) v += __shfl_down(v, off);
  if ((threadIdx.x & 63) == 0) ws_[threadIdx.x >> 6] = v;
  __syncthreads();
  if (threadIdx.x == 0) blkSum[blockIdx.x] = ws_[0] + ws_[1] + ws_[2] + ws_[3];
}

__global__ __launch_bounds__(512) void k_scanBlk(const int* __restrict__ blkSum, int* __restrict__ blkOff, int nblk) {
  __shared__ int s[512];
  int tid = threadIdx.x;
  int v = (tid < nblk) ? blkSum[tid] : 0;
  s[tid] = v;
  __syncthreads();
  for (int off = 1; off < 512; off <<= 1) {
    int t = (tid >= off) ? s[tid - off] : 0;
    __syncthreads();
    s[tid] += t;
    __syncthreads();
  }
  if (tid < nblk) blkOff[tid] = s[tid] - v;   // exclusive
}

__global__ __launch_bounds__(256) void k_writeOff(const int* __restrict__ deg, const int* __restrict__ blkOff,
                                                  int* __restrict__ dstOff, int* __restrict__ cur) {
  __shared__ int s[256];
  int i = blockIdx.x * 256 + threadIdx.x;
  int tid = threadIdx.x;
  int v = (i < N_) ? deg[i] : 0;
  s[tid] = v;
  __syncthreads();
  for (int off = 1; off < 256; off <<= 1) {
    int t = (tid >= off) ? s[tid - off] : 0;
    __syncthreads();
    s[tid] += t;
    __syncthreads();
  }
  int e = blkOff[blockIdx.x] + s[tid] - v;    // global exclusive prefix
  if (i < N_) { dstOff[i] = e; cur[i] = e; }
  else if (i == N_) dstOff[N_] = e;
}

__global__ __launch_bounds__(256) void k_scatterDst(const int* __restrict__ dstS,
                                                    const int* __restrict__ padOff, int* __restrict__ cur,
                                                    int* __restrict__ posbuf, int plo, int phi) {
  int p = plo + blockIdx.x * 256 + threadIdx.x;
  if (p >= phi || p >= padOff[R_]) return;
  int d = dstS[p];
  if (d < 0) return;                 // padding slot
  int j = atomicAdd(&cur[d], 1);
  posbuf[j] = p;
}

__global__ __launch_bounds__(256) void k_copyBound(const int* __restrict__ cur, int* __restrict__ bnd) {
  int d = blockIdx.x * 256 + threadIdx.x;
  if (d < N_) bnd[d] = cur[d];
}

// ---------------- per-edge mean-norm from dst-sorted segments ----------------

__global__ __launch_bounds__(256) void k_norm(const int* __restrict__ posbuf, const int* __restrict__ dstOff,
                                              const int* __restrict__ tileRel, float* __restrict__ normS) {
  __shared__ int rels[4][128];
  int d = blockIdx.x * 4 + (threadIdx.x >> 6);
  int sub = threadIdx.x >> 6;
  int l = threadIdx.x & 63;
  int s0 = 0, deg = 0;
  if (d < N_) { s0 = dstOff[d]; deg = dstOff[d + 1] - s0; }
  int cap = deg < 128 ? deg : 128;
  int myp[4]; int myr[4];
  for (int j = l, t = 0; j < cap; j += 64, ++t) {
    int p = posbuf[s0 + j];
    int r = tileRel[p >> 6];
    rels[sub][j] = r;
    if (t < 4) { myp[t] = p; myr[t] = r; }
  }
  __syncthreads();
  if (d >= N_) return;
  for (int j = l, t = 0; j < deg; j += 64, ++t) {
    int p, r;
    if (j < 128 && t < 4) { p = myp[t]; r = myr[t]; }
    else { p = posbuf[s0 + j]; r = tileRel[p >> 6]; }
    int cnt = 0;
    for (int k = 0; k < deg; k++) {
      int rk = (k < 128) ? rels[sub][k] : tileRel[posbuf[s0 + k] >> 6];
      cnt += (rk == r) ? 1 : 0;
    }
    normS[p] = 1.0f / (float)(cnt > 0 ? cnt : 1);
  }
}

// ---------------- W_r = sum_b comp[r,b]*basis[b]; pack to B-fragment order ----------------

__global__ __launch_bounds__(256) void k_computeW(const float* __restrict__ comp, const float* __restrict__ basis,
                                                  float* __restrict__ W) {
  __shared__ float c[B_];
  int r = blockIdx.x >> 6;
  int chunk = blockIdx.x & 63;
  if (threadIdx.x < B_) c[threadIdx.x] = comp[r * B_ + threadIdx.x];
  __syncthreads();
  int ij = chunk * 256 + threadIdx.x;
  float acc = 0.f;
#pragma unroll 10
  for (int b = 0; b < B_; b++) acc += c[b] * basis[b * (D_ * D_) + ij];
  W[r * (D_ * D_) + ij] = acc;
}

// pack: Wpack[r][ks][cg][lane][j] = bf16(W[r][ks*32+(lane>>4)*8+j][cg*16+(lane&15)])
__global__ __launch_bounds__(256) void k_packW(const float* __restrict__ W, ushort* __restrict__ Wpack) {
  int r = blockIdx.x;
  const float* Wr = W + (size_t)r * (D_ * D_);
  ushort* out = Wpack + (size_t)r * (D_ * D_);
  for (int i = threadIdx.x; i < D_ * D_; i += 256) {
    int j = i & 7, l = (i >> 3) & 63, cg = (i >> 9) & 7, ks = i >> 12;
    int k = ks * 32 + (l >> 4) * 8 + j;
    int n = cg * 16 + (l & 15);
    out[i] = f2bf(Wr[k * D_ + n]);
  }
}

__global__ __launch_bounds__(256) void k_cast(const float* __restrict__ x, ushort* __restrict__ xb, int n8) {
  int i = blockIdx.x * 256 + threadIdx.x;
  if (i >= n8) return;
  const float4* xp = (const float4*)(x + (size_t)i * 8);
  float4 a = xp[0], b = xp[1];
  uint4 pk;
  pk.x = (uint)f2bf(a.x) | ((uint)f2bf(a.y) << 16);
  pk.y = (uint)f2bf(a.z) | ((uint)f2bf(a.w) << 16);
  pk.z = (uint)f2bf(b.x) | ((uint)f2bf(b.y) << 16);
  pk.w = (uint)f2bf(b.z) | ((uint)f2bf(b.w) << 16);
  *(uint4*)(xb + (size_t)i * 8) = pk;
}

// ---------------- y = x @ root + bias (MFMA, fp32 out via LDS transpose) ----------------

__global__ __launch_bounds__(256, 2) void k_root_mfma(
    const ushort* __restrict__ xb, const ushort* __restrict__ rootPack,
    const float* __restrict__ bias, float* __restrict__ y, int nt) {
  __shared__ float stg[4][16 * 132];
  int tstart = blockIdx.x * RG_;
  if (tstart >= nt) return;
  int tend = tstart + RG_; if (tend > nt) tend = nt;
  int w = threadIdx.x >> 6, l = threadIdx.x & 63;
  int q = l >> 4, tx = l & 15;
  int r2 = l & 15, c2 = l >> 4;
  float* st = stg[w];
  s8b b[4][8];
  {
    const s8b* wp = (const s8b*)rootPack;
#pragma unroll
    for (int ks = 0; ks < 4; ++ks)
#pragma unroll
      for (int cg = 0; cg < 8; ++cg)
        b[ks][cg] = wp[(ks * 8 + cg) * 64 + l];
  }
  float bv[8];
#pragma unroll
  for (int cg = 0; cg < 8; ++cg) bv[cg] = bias[cg * 16 + tx];
  s8b a0, a1, a2, a3;
  {
    int gr = tstart * TE + 16 * w + tx; if (gr >= N_) gr = N_ - 1;
    const s8b* xr = (const s8b*)(xb + (size_t)gr * D_);
    a0 = xr[q]; a1 = xr[4 + q]; a2 = xr[8 + q]; a3 = xr[12 + q];
  }
  for (int tile = tstart; tile < tend; ++tile) {
    int base = tile * TE;
    s8b n0, n1, n2, n3;
    bool pre = (tile + 1 < tend);
    if (pre) {
      int gr = base + TE + 16 * w + tx; if (gr >= N_) gr = N_ - 1;
      const s8b* xn = (const s8b*)(xb + (size_t)gr * D_);
      n0 = xn[q]; n1 = xn[4 + q]; n2 = xn[8 + q]; n3 = xn[12 + q];
    }
    f32x4 acc[8];
#pragma unroll
    for (int cg = 0; cg < 8; ++cg) acc[cg] = (f32x4){0.f, 0.f, 0.f, 0.f};
#pragma unroll
    for (int cg = 0; cg < 8; ++cg) {
      acc[cg] = __builtin_amdgcn_mfma_f32_16x16x32_bf16(a0, b[0][cg], acc[cg], 0, 0, 0);
      acc[cg] = __builtin_amdgcn_mfma_f32_16x16x32_bf16(a1, b[1][cg], acc[cg], 0, 0, 0);
      acc[cg] = __builtin_amdgcn_mfma_f32_16x16x32_bf16(a2, b[2][cg], acc[cg], 0, 0, 0);
      acc[cg] = __builtin_amdgcn_mfma_f32_16x16x32_bf16(a3, b[3][cg], acc[cg], 0, 0, 0);
    }
#pragma unroll
    for (int cg = 0; cg < 8; ++cg)
#pragma unroll
      for (int r = 0; r < 4; ++r)
        st[(4 * q + r) * 132 + cg * 16 + tx] = acc[cg][r] + bv[cg];
    int gr = base + 16 * w + r2;
#pragma unroll
    for (int k = 0; k < 8; ++k) {
      int ch = c2 + 4 * k;          // 32 chunks of 4 floats; 64B-contig per instr
      float4 v = *(const float4*)&st[r2 * 132 + ch * 4];
      if (gr < N_) *(float4*)(y + (size_t)gr * D_ + ch * 4) = v;
    }
    if (pre) { a0 = n0; a1 = n1; a2 = n2; a3 = n3; }
  }
}

// ---------------- phase A: MFMA edge messages (LDS store transpose + prefetch) ----------------

__global__ __launch_bounds__(256, 2) void k_edges_mfma(
    const ushort* __restrict__ xb, const ushort* __restrict__ Wpack,
    const int* __restrict__ srcS, const float* __restrict__ normS,
    const int* __restrict__ tileRel, const int* __restrict__ padOff,
    ushort* __restrict__ msg, int tile0, int tile1) {
  __shared__ ushort stg[4][16 * 130];
  int padTot = padOff[R_];
  int tstart = tile0 + blockIdx.x * G_;
  if (tstart >= tile1 || tstart * TE >= padTot) return;
  int tend = tstart + G_; if (tend > tile1) tend = tile1;
  int w = threadIdx.x >> 6, l = threadIdx.x & 63;
  int q = l >> 4, tx = l & 15;
  int r2 = l & 15, c2 = l >> 4;
  ushort* st = stg[w];
  int curRel = -1;
  s8b b[4][8];
  s8b a0, a1, a2, a3;
  {
    int sr = srcS[tstart * TE + 16 * w + tx];
    const s8b* xr = (const s8b*)(xb + (size_t)sr * D_);
    a0 = xr[q]; a1 = xr[4 + q]; a2 = xr[8 + q]; a3 = xr[12 + q];
  }
  for (int tile = tstart; tile < tend; ++tile) {
    int base = tile * TE;
    if (base >= padTot) break;
    int rel = tileRel[tile];
    if (rel != curRel) {
      curRel = rel;
      const s8b* wp = (const s8b*)(Wpack + (size_t)rel * (D_ * D_));
#pragma unroll
      for (int ks = 0; ks < 4; ++ks)
#pragma unroll
        for (int cg = 0; cg < 8; ++cg)
          b[ks][cg] = wp[(ks * 8 + cg) * 64 + l];
    }
    float nv[4];
#pragma unroll
    for (int r = 0; r < 4; ++r) nv[r] = normS[base + 16 * w + 4 * q + r];
    // prefetch next tile's A fragments (hidden under this tile's MFMAs)
    s8b n0, n1, n2, n3;
    int nb = base + TE;
    bool pre = (tile + 1 < tend) && (nb < padTot);
    if (pre) {
      int sr = srcS[nb + 16 * w + tx];
      const s8b* xn = (const s8b*)(xb + (size_t)sr * D_);
      n0 = xn[q]; n1 = xn[4 + q]; n2 = xn[8 + q]; n3 = xn[12 + q];
    }
    f32x4 acc[8];
#pragma unroll
    for (int cg = 0; cg < 8; ++cg) acc[cg] = (f32x4){0.f, 0.f, 0.f, 0.f};
#pragma unroll
    for (int cg = 0; cg < 8; ++cg) {
      acc[cg] = __builtin_amdgcn_mfma_f32_16x16x32_bf16(a0, b[0][cg], acc[cg], 0, 0, 0);
      acc[cg] = __builtin_amdgcn_mfma_f32_16x16x32_bf16(a1, b[1][cg], acc[cg], 0, 0, 0);
      acc[cg] = __builtin_amdgcn_mfma_f32_16x16x32_bf16(a2, b[2][cg], acc[cg], 0, 0, 0);
      acc[cg] = __builtin_amdgcn_mfma_f32_16x16x32_bf16(a3, b[3][cg], acc[cg], 0, 0, 0);
    }
    // stage to wave-private LDS (2B writes, ~2-way banks = free)
#pragma unroll
    for (int cg = 0; cg < 8; ++cg)
#pragma unroll
      for (int r = 0; r < 4; ++r)
        st[(4 * q + r) * 130 + cg * 16 + tx] = f2bf(acc[cg][r] * nv[r]);
    // read back row-contiguous and store coalesced (16B/lane, 64B-contig per instr per row)
    ushort* mrow = msg + (size_t)(base - tile0 * TE + 16 * w + r2) * D_;
#pragma unroll
    for (int k = 0; k < 4; ++k) {
      int ch = c2 * 4 + k;
      uint4 v = *(const uint4*)&st[r2 * 130 + ch * 8];
      *(uint4*)(mrow + ch * 8) = v;
    }
    if (pre) { a0 = n0; a1 = n1; a2 = n2; a3 = n3; }
  }
}

// ---------------- phase B: wave-per-dst aggregation ----------------

__global__ __launch_bounds__(256) void k_agg2(const ushort* __restrict__ msg, const int* __restrict__ posbuf,
                                              const int* __restrict__ jlo, const int* __restrict__ jhi,
                                              float* __restrict__ y, int plo, int final_) {
  int d = blockIdx.x * 4 + (threadIdx.x >> 6);
  if (d >= N_) return;
  int l = threadIdx.x & 63, sub = l >> 4, tx = l & 15;
  int s0 = jlo[d], s1 = jhi[d];
  float acc[8];
#pragma unroll
  for (int i = 0; i < 8; ++i) acc[i] = 0.f;
  for (int j = s0 + sub; j < s1; j += 4) {
    int p = posbuf[j];
    uint4 mv = *(const uint4*)(msg + (((size_t)(p - plo)) << 7) + (tx << 3));
    acc[0] += bf2f((ushort)mv.x); acc[1] += bf2f((ushort)(mv.x >> 16));
    acc[2] += bf2f((ushort)mv.y); acc[3] += bf2f((ushort)(mv.y >> 16));
    acc[4] += bf2f((ushort)mv.z); acc[5] += bf2f((ushort)(mv.z >> 16));
    acc[6] += bf2f((ushort)mv.w); acc[7] += bf2f((ushort)(mv.w >> 16));
  }
#pragma unroll
  for (int i = 0; i < 8; ++i) {
    acc[i] += __shfl_xor(acc[i], 16);
    acc[i] += __shfl_xor(acc[i], 32);
  }
  if (sub == 0) {
    float* yp = y + (((size_t)d) << 7) + (tx << 3);
    float4 y0 = *(float4*)yp, y1 = *(float4*)(yp + 4);
    y0.x += acc[0]; y0.y += acc[1]; y0.z += acc[2]; y0.w += acc[3];
    y1.x += acc[4]; y1.y += acc[5]; y1.z += acc[6]; y1.w += acc[7];
    if (final_) {
      y0.x = fmaxf(y0.x, 0.f); y0.y = fmaxf(y0.y, 0.f); y0.z = fmaxf(y0.z, 0.f); y0.w = fmaxf(y0.w, 0.f);
      y1.x = fmaxf(y1.x, 0.f); y1.y = fmaxf(y1.y, 0.f); y1.z = fmaxf(y1.z, 0.f); y1.w = fmaxf(y1.w, 0.f);
    }
    *(float4*)yp = y0; *(float4*)(yp + 4) = y1;
  }
}

// ---------------- launch ----------------

extern "C" void kernel_launch(void* const* d_in, const int* in_sizes, int n_in,
                              void* d_out, int out_size, void* d_ws, size_t ws_size,
                              hipStream_t stream) {
  const float* entity = (const float*)d_in[0];
  const float* comp   = (const float*)d_in[1];
  const float* basis  = (const float*)d_in[2];
  const float* root   = (const float*)d_in[3];
  const float* bias   = (const float*)d_in[4];
  const int*   eidx   = (const int*)d_in[5];
  const int*   etype  = (const int*)d_in[6];
  const int E = in_sizes[6];
  const int* src = eidx;
  const int* dst = eidx + E;

  char* ws = (char*)d_ws;
  const size_t Epad = (size_t)E + (size_t)R_ * TE;
  const int uTiles = (E + TE - 1) / TE + R_;
  const int NBLK = (N_ + 1 + 255) / 256;
  auto al = [](size_t x) { return (x + 255) & ~(size_t)255; };

  size_t o_Wpack  = 0;
  size_t o_srcS   = al(o_Wpack + (size_t)(R_ + 1) * D_ * D_ * 2);   // +1 slot for packed root
  size_t o_normS  = al(o_srcS + Epad * 4);
  size_t o_posbuf = al(o_normS + Epad * 4);
  size_t o_degDst = al(o_posbuf + (size_t)E * 4);
  size_t o_dstOff = al(o_degDst + (size_t)N_ * 4);
  size_t o_cursD  = al(o_dstOff + (size_t)(N_ + 8) * 4);
  size_t o_bounds = al(o_cursD + (size_t)N_ * 4);
  size_t o_tileRel= al(o_bounds + (size_t)MAXC * N_ * 4);
  size_t o_small  = al(o_tileRel + (size_t)uTiles * 4);
  size_t o_x1     = al(o_small + 8192);
  size_t o_xb     = al(o_x1 + (size_t)N_ * D_ * 4);
  size_t o_msg    = al(o_xb + (size_t)N_ * D_ * 2);

  // aliases inside the msg region (all dead before first msg write):
  size_t o_dstS   = o_msg;                 // Epad*4, dead after k_scatterDst passes
  size_t o_Wf     = al(o_msg + Epad * 4);  // per-layer, dead after k_packW (before msg writes)

  ushort* Wpack  = (ushort*)(ws + o_Wpack);
  int*    srcS   = (int*)(ws + o_srcS);
  float*  normS  = (float*)(ws + o_normS);
  int*    posbuf = (int*)(ws + o_posbuf);
  int*    degDst = (int*)(ws + o_degDst);
  int*    dstOff = (int*)(ws + o_dstOff);
  int*    cursD  = (int*)(ws + o_cursD);
  int*    bounds = (int*)(ws + o_bounds);
  int*    tileRel= (int*)(ws + o_tileRel);
  int*    hist   = (int*)(ws + o_small);
  int*    padOff = hist + 256;
  int*    cursor = hist + 512;
  int*    blkSum = hist + 768;
  int*    blkOff = hist + 1280;
  float*  x1     = (float*)(ws + o_x1);
  ushort* xb     = (ushort*)(ws + o_xb);
  int*    dstS   = (int*)(ws + o_dstS);
  float*  Wf     = (float*)(ws + o_Wf);
  ushort* msg    = (ushort*)(ws + o_msg);
  ushort* rootPack = Wpack + (size_t)R_ * D_ * D_;

  hipMemsetAsync(ws + o_srcS, 0, Epad * 4, stream);
  hipMemsetAsync(ws + o_degDst, 0, (size_t)N_ * 4, stream);
  hipMemsetAsync(ws + o_small, 0, 8192, stream);
  hipMemsetAsync(ws + o_dstS, 0xFF, Epad * 4, stream);

  int gH = (E + 4095) / 4096;
  int gE = (E + 255) / 256;
  k_hist<<<gH, 256, 0, stream>>>(etype, E, hist);
  k_scanRel<<<1, 256, 0, stream>>>(hist, padOff, cursor);
  k_scatter<<<gH, 256, 0, stream>>>(src, dst, etype, E, cursor, srcS, dstS);
  k_tileRel<<<(uTiles + 255) / 256, 256, 0, stream>>>(padOff, tileRel, uTiles);
  k_countDst<<<gE, 256, 0, stream>>>(dst, E, degDst);
  k_degPart<<<NBLK, 256, 0, stream>>>(degDst, blkSum);
  k_scanBlk<<<1, 512, 0, stream>>>(blkSum, blkOff, NBLK);
  k_writeOff<<<NBLK, 256, 0, stream>>>(degDst, blkOff, dstOff, cursD);

  // chunking from ws capacity
  size_t cap = (ws_size > o_msg + 16384) ? (ws_size - o_msg) : (size_t)16384;
  size_t tileBytes = (size_t)TE * D_ * 2;
  long long maxT = (long long)(cap / tileBytes);
  if (maxT < 1) maxT = 1;
  int nch = (int)((uTiles + maxT - 1) / maxT);
  if (nch < 1) nch = 1;
  if (nch > MAXC) nch = MAXC;
  int chunkTiles = (uTiles + nch - 1) / nch;
  nch = (uTiles + chunkTiles - 1) / chunkTiles;

  // chunk-major posbuf: scatter per chunk, snapshot cursors
  for (int c = 0; c < nch; c++) {
    int plo = c * chunkTiles * TE;
    int phi = (c + 1) * chunkTiles * TE; if (phi > uTiles * TE) phi = uTiles * TE;
    int gS = (phi - plo + 255) / 256;
    if (gS > 0)
      k_scatterDst<<<gS, 256, 0, stream>>>(dstS, padOff, cursD, posbuf, plo, phi);
    k_copyBound<<<(N_ + 255) / 256, 256, 0, stream>>>(cursD, bounds + (size_t)c * N_);
  }

  k_norm<<<(N_ + 3) / 4, 256, 0, stream>>>(posbuf, dstOff, tileRel, normS);

  int ntR = (N_ + TE - 1) / TE;
  int gAgg = (N_ + 3) / 4;
  for (int l = 0; l < 2; l++) {
    const float* xin = l ? x1 : entity;
    float* yout = l ? (float*)d_out : x1;
    k_computeW<<<R_ * 64, 256, 0, stream>>>(comp + l * R_ * B_, basis + (size_t)l * B_ * D_ * D_, Wf);
    k_packW<<<R_, 256, 0, stream>>>(Wf, Wpack);
    k_packW<<<1, 256, 0, stream>>>(root + (size_t)l * D_ * D_, rootPack);
    k_cast<<<(N_ * D_ / 8 + 255) / 256, 256, 0, stream>>>(xin, xb, N_ * D_ / 8);
    k_root_mfma<<<(ntR + RG_ - 1) / RG_, 256, 0, stream>>>(xb, rootPack, bias + l * D_, yout, ntR);
    for (int c = 0; c < nch; c++) {
      int t0 = c * chunkTiles;
      int t1 = t0 + chunkTiles; if (t1 > uTiles) t1 = uTiles;
      int gB = (t1 - t0 + G_ - 1) / G_;
      k_edges_mfma<<<gB, 256, 0, stream>>>(xb, Wpack, srcS, normS, tileRel, padOff, msg, t0, t1);
      const int* jlo = (c == 0) ? dstOff : bounds + (size_t)(c - 1) * N_;
      const int* jhi = bounds + (size_t)c * N_;
      k_agg2<<<gAgg, 256, 0, stream>>>(msg, posbuf, jlo, jhi, yout, t0 * TE, c == nch - 1);
    }
  }
}